// Round 5
// baseline (1978.145 us; speedup 1.0000x reference)
//
#include <hip/hip_runtime.h>

#define DD 256

typedef unsigned short u16;
typedef unsigned int u32;
using bf16x8 = __attribute__((ext_vector_type(8))) short;  // 8 bf16 (4 VGPRs)
using f32x4  = __attribute__((ext_vector_type(4))) float;

// ---- bfx2 helpers: uint32 = hi_bf16 (bits 15:0) | lo_bf16 (bits 31:16) ----

__device__ __forceinline__ u32 f2bfx2(float v) {
  u32 b = __float_as_uint(v);
  u32 hi = (b + 0x7fffu + ((b >> 16) & 1u)) >> 16;  // RNE bf16
  float hf = __uint_as_float(hi << 16);
  float lof = v - hf;
  u32 b2 = __float_as_uint(lof);
  u32 lo = (b2 + 0x7fffu + ((b2 >> 16) & 1u)) >> 16;
  return hi | (lo << 16);
}

__device__ __forceinline__ float bfx2_to_f(u32 e) {
  return __uint_as_float(e << 16) + __uint_as_float(e & 0xffff0000u);
}

__device__ __forceinline__ bf16x8 as_bf16x8(uint4 u) {
  union { uint4 u; bf16x8 v; } c;
  c.u = u;
  return c.v;
}

// deinterleave 8 packed bfx2 (a,b) into hi-plane / lo-plane bf16x8
__device__ __forceinline__ void unpack8(uint4 a, uint4 b, bf16x8& hi, bf16x8& lo) {
  union { u32 w[4]; bf16x8 v; } H, L;
  H.w[0] = __builtin_amdgcn_perm(a.y, a.x, 0x05040100u);
  L.w[0] = __builtin_amdgcn_perm(a.y, a.x, 0x07060302u);
  H.w[1] = __builtin_amdgcn_perm(a.w, a.z, 0x05040100u);
  L.w[1] = __builtin_amdgcn_perm(a.w, a.z, 0x07060302u);
  H.w[2] = __builtin_amdgcn_perm(b.y, b.x, 0x05040100u);
  L.w[2] = __builtin_amdgcn_perm(b.y, b.x, 0x07060302u);
  H.w[3] = __builtin_amdgcn_perm(b.w, b.z, 0x05040100u);
  L.w[3] = __builtin_amdgcn_perm(b.w, b.z, 0x07060302u);
  hi = H.v;
  lo = L.v;
}

// ---------------- CSR build ----------------

__global__ void zero_i32_kernel(int* p, int n) {
  int i = blockIdx.x * 256 + threadIdx.x;
  if (i < n) p[i] = 0;
}

__global__ void zero_f32_kernel(float* p, int n) {
  int i = blockIdx.x * 256 + threadIdx.x;
  if (i < n) p[i] = 0.f;
}

__global__ void count_kernel(const int* __restrict__ dst, int* __restrict__ cnt, int e) {
  int i = blockIdx.x * 256 + threadIdx.x;
  if (i < e) atomicAdd(&cnt[dst[i]], 1);
}

__global__ void scan_block_kernel(const int* __restrict__ cnt, int* __restrict__ out,
                                  int* __restrict__ bsum, int n) {
  __shared__ int sh[256];
  int tid = threadIdx.x;
  int base = blockIdx.x * 1024 + tid * 4;
  int v0 = (base + 0 < n) ? cnt[base + 0] : 0;
  int v1 = (base + 1 < n) ? cnt[base + 1] : 0;
  int v2 = (base + 2 < n) ? cnt[base + 2] : 0;
  int v3 = (base + 3 < n) ? cnt[base + 3] : 0;
  int s = v0 + v1 + v2 + v3;
  sh[tid] = s;
  __syncthreads();
  for (int d = 1; d < 256; d <<= 1) {
    int t = (tid >= d) ? sh[tid - d] : 0;
    __syncthreads();
    sh[tid] += t;
    __syncthreads();
  }
  int excl = sh[tid] - s;
  if (base + 0 < n) out[base + 0] = excl;
  excl += v0;
  if (base + 1 < n) out[base + 1] = excl;
  excl += v1;
  if (base + 2 < n) out[base + 2] = excl;
  excl += v2;
  if (base + 3 < n) out[base + 3] = excl;
  if (tid == 255) bsum[blockIdx.x] = sh[255];
}

__global__ void scan_partials_kernel(int* bsum, int nb) {
  if (threadIdx.x == 0 && blockIdx.x == 0) {
    int acc = 0;
    for (int i = 0; i < nb; ++i) { int t = bsum[i]; bsum[i] = acc; acc += t; }
  }
}

__global__ void finalize_kernel(int* __restrict__ off, const int* __restrict__ bsum,
                                int* __restrict__ cursor, const int* __restrict__ cnt,
                                float* __restrict__ dis, int n, int e) {
  int i = blockIdx.x * 256 + threadIdx.x;
  if (i < n) {
    int o = off[i] + bsum[i >> 10];
    off[i] = o;
    cursor[i] = o;
    dis[i] = rsqrtf((float)(cnt[i] + 1));  // deg includes self-loop
  }
  if (i == 0 && blockIdx.x == 0) off[n] = e;
}

__global__ void fill_kernel(const int* __restrict__ src, const int* __restrict__ dst,
                            int* __restrict__ cursor, int* __restrict__ csr_src, int e) {
  int i = blockIdx.x * 256 + threadIdx.x;
  if (i < e) {
    int d = dst[i];
    int p = atomicAdd(&cursor[d], 1);
    csr_src[p] = src[i];
  }
}

// ---------------- weight prep (batched, coalesced writes) ----------------

__global__ void wsplit_all_kernel(const float* __restrict__ fl_W, const float* __restrict__ conv1_W,
                                  const float* __restrict__ convs_W, u16* __restrict__ flHi,
                                  u16* __restrict__ flLo, u16* __restrict__ cvHi,
                                  u16* __restrict__ cvLo) {
  int j = blockIdx.x;   // output column
  int m = blockIdx.y;   // matrix id
  int k = threadIdx.x;  // input row
  if (m == 0) {
    if (k < 128) {
      u32 p = f2bfx2(fl_W[(size_t)k * 256 + j]);
      flHi[(size_t)j * 128 + k] = (u16)(p & 0xffffu);
      flLo[(size_t)j * 128 + k] = (u16)(p >> 16);
    }
  } else {
    int c = m - 1;
    const float* W = (c == 0) ? conv1_W : convs_W + (size_t)(c - 1) * 65536;
    u32 p = f2bfx2(W[(size_t)k * 256 + j]);
    cvHi[(size_t)c * 65536 + (size_t)j * 256 + k] = (u16)(p & 0xffffu);
    cvLo[(size_t)c * 65536 + (size_t)j * 256 + k] = (u16)(p >> 16);
  }
}

// tr prep: W' = diag(scale)@Wt split/transposed; bias_out = bt + shift@Wt. grid 256.
__global__ void wsplit_fold_kernel(const float* __restrict__ W, const float* __restrict__ scale,
                                   const float* __restrict__ shift, const float* __restrict__ bt,
                                   u16* __restrict__ WhiT, u16* __restrict__ WloT,
                                   float* __restrict__ bias_out) {
  __shared__ float red[256];
  int j = blockIdx.x;
  int k = threadIdx.x;
  float w = W[(size_t)k * 256 + j];
  u32 p = f2bfx2(w * scale[k]);
  WhiT[(size_t)j * 256 + k] = (u16)(p & 0xffffu);
  WloT[(size_t)j * 256 + k] = (u16)(p >> 16);
  red[k] = shift[k] * w;
  __syncthreads();
  for (int d = 128; d > 0; d >>= 1) {
    if (k < d) red[k] += red[k + d];
    __syncthreads();
  }
  if (k == 0) bias_out[j] = bt[j] + red[0];
}

// ---------------- MFMA GEMM, no LDS / no barriers ----------------
// C[n][256] = act(A[n][K] @ W[K][256] + bias); A bfx2 (or fp32 if AF32),
// W pre-split/transposed [col][k] hi/lo planes. Split product:
// ah*bh + ah*bl + al*bh (fp32 acc) ~ fp32 precision.
// Block = 64 rows x 128 cols (grid.y selects col-half); 4 waves, wave owns
// 32 cols -> acc 4x2 (32 f32 regs) for higher occupancy / latency hiding.

template <int K, bool RELU, bool AF32>
__global__ __launch_bounds__(256) void gemm_mfma_kernel(
    const void* __restrict__ Av, const u16* __restrict__ WhiT, const u16* __restrict__ WloT,
    const float* __restrict__ bias, u32* __restrict__ C, int nrows) {
  const int tid = threadIdx.x;
  const int lane = tid & 63;
  const int wave = tid >> 6;
  const int row0 = blockIdx.x * 64;
  const int colb = blockIdx.y * 128 + wave * 32;
  const int q = lane >> 4;
  const int r16 = lane & 15;

  int aOff[4];
#pragma unroll
  for (int i = 0; i < 4; ++i) {
    int row = row0 + i * 16 + r16;
    if (row > nrows - 1) row = nrows - 1;
    aOff[i] = row * K + q * 8;
  }
  int bOff[2];
#pragma unroll
  for (int r = 0; r < 2; ++r) bOff[r] = (colb + r * 16 + r16) * K + q * 8;

  f32x4 acc[4][2];
#pragma unroll
  for (int i = 0; i < 4; ++i)
#pragma unroll
    for (int r = 0; r < 2; ++r) acc[i][r] = (f32x4){0.f, 0.f, 0.f, 0.f};

  auto loadA = [&](int k0, uint4 (&dst)[4][2]) {
#pragma unroll
    for (int i = 0; i < 4; ++i) {
      if (AF32) {
        const float* ap = (const float*)Av + aOff[i] + k0;
        float4 f0 = *(const float4*)ap;
        float4 f1 = *(const float4*)(ap + 4);
        dst[i][0] = make_uint4(f2bfx2(f0.x), f2bfx2(f0.y), f2bfx2(f0.z), f2bfx2(f0.w));
        dst[i][1] = make_uint4(f2bfx2(f1.x), f2bfx2(f1.y), f2bfx2(f1.z), f2bfx2(f1.w));
      } else {
        const u32* ap = (const u32*)Av + aOff[i] + k0;
        dst[i][0] = *(const uint4*)ap;
        dst[i][1] = *(const uint4*)(ap + 4);
      }
    }
  };
  auto loadB = [&](int k0, uint4 (&bh)[2], uint4 (&bl)[2]) {
#pragma unroll
    for (int r = 0; r < 2; ++r) {
      bh[r] = *(const uint4*)(WhiT + bOff[r] + k0);
      bl[r] = *(const uint4*)(WloT + bOff[r] + k0);
    }
  };

  uint4 curA[4][2], curBH[2], curBL[2];
  loadA(0, curA);
  loadB(0, curBH, curBL);

#pragma unroll
  for (int k0 = 0; k0 < K; k0 += 32) {
    uint4 nxtA[4][2], nxtBH[2], nxtBL[2];
    if (k0 + 32 < K) {
      loadA(k0 + 32, nxtA);
      loadB(k0 + 32, nxtBH, nxtBL);
    }
    bf16x8 ah[4], al[4];
#pragma unroll
    for (int i = 0; i < 4; ++i) unpack8(curA[i][0], curA[i][1], ah[i], al[i]);
#pragma unroll
    for (int r = 0; r < 2; ++r) {
      bf16x8 bh = as_bf16x8(curBH[r]);
      bf16x8 bl = as_bf16x8(curBL[r]);
#pragma unroll
      for (int i = 0; i < 4; ++i) {
        acc[i][r] = __builtin_amdgcn_mfma_f32_16x16x32_bf16(ah[i], bh, acc[i][r], 0, 0, 0);
        acc[i][r] = __builtin_amdgcn_mfma_f32_16x16x32_bf16(ah[i], bl, acc[i][r], 0, 0, 0);
        acc[i][r] = __builtin_amdgcn_mfma_f32_16x16x32_bf16(al[i], bh, acc[i][r], 0, 0, 0);
      }
    }
    if (k0 + 32 < K) {
#pragma unroll
      for (int i = 0; i < 4; ++i) {
        curA[i][0] = nxtA[i][0];
        curA[i][1] = nxtA[i][1];
      }
#pragma unroll
      for (int r = 0; r < 2; ++r) {
        curBH[r] = nxtBH[r];
        curBL[r] = nxtBL[r];
      }
    }
  }

  // epilogue: C/D layout col=lane&15, row=(lane>>4)*4+reg
#pragma unroll
  for (int r = 0; r < 2; ++r) {
    int col = colb + r * 16 + r16;
    float bv = bias ? bias[col] : 0.f;
#pragma unroll
    for (int i = 0; i < 4; ++i) {
#pragma unroll
      for (int g = 0; g < 4; ++g) {
        int row = row0 + i * 16 + q * 4 + g;
        if (row < nrows) {
          float v = acc[i][r][g] + bv;
          if (RELU) v = fmaxf(v, 0.f);
          C[(size_t)row * 256 + col] = f2bfx2(v);
        }
      }
    }
  }
}

// ---------------- GCN gather (bfx2 in/out), 4-edge unroll ----------------

__global__ __launch_bounds__(256) void gather_kernel(
    const u32* __restrict__ m, const int* __restrict__ off,
    const int* __restrict__ csr_src, const float* __restrict__ dis,
    const float* __restrict__ bias, u32* __restrict__ out, int n) {
  int node = blockIdx.x * 4 + (threadIdx.x >> 6);
  if (node >= n) return;
  int lane = threadIdx.x & 63;
  float di = dis[node];
  uint4 v = *(const uint4*)(m + (size_t)node * DD + lane * 4);
  float w = di * di;
  float ax = w * bfx2_to_f(v.x), ay = w * bfx2_to_f(v.y);
  float az = w * bfx2_to_f(v.z), aw = w * bfx2_to_f(v.w);
  int e0 = off[node], e1 = off[node + 1];
  int e = e0;
  for (; e + 3 < e1; e += 4) {
    int s0 = csr_src[e], s1 = csr_src[e + 1], s2 = csr_src[e + 2], s3 = csr_src[e + 3];
    float w0 = dis[s0] * di, w1 = dis[s1] * di, w2 = dis[s2] * di, w3 = dis[s3] * di;
    uint4 u0 = *(const uint4*)(m + (size_t)s0 * DD + lane * 4);
    uint4 u1 = *(const uint4*)(m + (size_t)s1 * DD + lane * 4);
    uint4 u2 = *(const uint4*)(m + (size_t)s2 * DD + lane * 4);
    uint4 u3 = *(const uint4*)(m + (size_t)s3 * DD + lane * 4);
    ax = fmaf(w0, bfx2_to_f(u0.x), ax); ay = fmaf(w0, bfx2_to_f(u0.y), ay);
    az = fmaf(w0, bfx2_to_f(u0.z), az); aw = fmaf(w0, bfx2_to_f(u0.w), aw);
    ax = fmaf(w1, bfx2_to_f(u1.x), ax); ay = fmaf(w1, bfx2_to_f(u1.y), ay);
    az = fmaf(w1, bfx2_to_f(u1.z), az); aw = fmaf(w1, bfx2_to_f(u1.w), aw);
    ax = fmaf(w2, bfx2_to_f(u2.x), ax); ay = fmaf(w2, bfx2_to_f(u2.y), ay);
    az = fmaf(w2, bfx2_to_f(u2.z), az); aw = fmaf(w2, bfx2_to_f(u2.w), aw);
    ax = fmaf(w3, bfx2_to_f(u3.x), ax); ay = fmaf(w3, bfx2_to_f(u3.y), ay);
    az = fmaf(w3, bfx2_to_f(u3.z), az); aw = fmaf(w3, bfx2_to_f(u3.w), aw);
  }
  for (; e < e1; ++e) {
    int s0 = csr_src[e];
    float w0 = dis[s0] * di;
    uint4 u0 = *(const uint4*)(m + (size_t)s0 * DD + lane * 4);
    ax = fmaf(w0, bfx2_to_f(u0.x), ax); ay = fmaf(w0, bfx2_to_f(u0.y), ay);
    az = fmaf(w0, bfx2_to_f(u0.z), az); aw = fmaf(w0, bfx2_to_f(u0.w), aw);
  }
  float4 bb = *(const float4*)(bias + lane * 4);
  uint4 oo;
  oo.x = f2bfx2(fmaxf(ax + bb.x, 0.f));
  oo.y = f2bfx2(fmaxf(ay + bb.y, 0.f));
  oo.z = f2bfx2(fmaxf(az + bb.z, 0.f));
  oo.w = f2bfx2(fmaxf(aw + bb.w, 0.f));
  *(uint4*)(out + (size_t)node * DD + lane * 4) = oo;
}

// ---------------- BatchNorm stats ----------------

__global__ void bn_partial_kernel(const u32* __restrict__ h, float* __restrict__ sums, int n) {
  int c = threadIdx.x;
  float s = 0.f, q = 0.f;
  for (int r = blockIdx.x; r < n; r += gridDim.x) {
    float v = bfx2_to_f(h[(size_t)r * DD + c]);
    s += v;
    q += v * v;
  }
  atomicAdd(&sums[c], s);
  atomicAdd(&sums[DD + c], q);
}

__global__ void bn_finalize_kernel(const float* __restrict__ sums, const float* __restrict__ g,
                                   const float* __restrict__ b, float* __restrict__ scale,
                                   float* __restrict__ shift, float inv_n) {
  int c = threadIdx.x;
  float mu = sums[c] * inv_n;
  float var = sums[DD + c] * inv_n - mu * mu;
  float inv = rsqrtf(var + 1e-5f);
  float sc = g[c] * inv;
  scale[c] = sc;
  shift[c] = b[c] - mu * sc;
}

// ---------------- global mean pool ----------------

__global__ void pool_kernel(const u32* __restrict__ h, const int* __restrict__ batch,
                            float* __restrict__ pooled, int n) {
  int g = blockIdx.x;
  int c = threadIdx.x;
  int lo = 0, hi = n;
  while (lo < hi) { int mid = (lo + hi) >> 1; if (batch[mid] < g) lo = mid + 1; else hi = mid; }
  int start = lo;
  hi = n;
  while (lo < hi) { int mid = (lo + hi) >> 1; if (batch[mid] <= g) lo = mid + 1; else hi = mid; }
  int end = lo;
  float a0 = 0.f, a1 = 0.f, a2 = 0.f, a3 = 0.f;
  int r = start;
  for (; r + 3 < end; r += 4) {
    a0 += bfx2_to_f(h[(size_t)(r + 0) * DD + c]);
    a1 += bfx2_to_f(h[(size_t)(r + 1) * DD + c]);
    a2 += bfx2_to_f(h[(size_t)(r + 2) * DD + c]);
    a3 += bfx2_to_f(h[(size_t)(r + 3) * DD + c]);
  }
  for (; r < end; ++r) a0 += bfx2_to_f(h[(size_t)r * DD + c]);
  float s = (a0 + a1) + (a2 + a3);
  int cg = end - start;
  pooled[g * DD + c] = s / (float)(cg > 1 ? cg : 1);
}

// ---------------- MLP head ----------------

__global__ void mlp1_kernel(const float* __restrict__ pooled, const float* __restrict__ W,
                            const float* __restrict__ b, float* __restrict__ out) {
  __shared__ float p[256];
  int g = blockIdx.x;
  int j = blockIdx.y * 256 + threadIdx.x;
  p[threadIdx.x] = pooled[g * 256 + threadIdx.x];
  __syncthreads();
  float acc = b[j];
#pragma unroll 8
  for (int k = 0; k < 512; ++k) acc = fmaf(p[k & 255], W[k * 512 + j], acc);
  out[g * 512 + j] = fmaxf(acc, 0.f);
}

__global__ void mlp2_kernel(const float* __restrict__ z1, const float* __restrict__ W,
                            const float* __restrict__ b, float* __restrict__ out) {
  __shared__ float p[512];
  int g = blockIdx.x;
  p[threadIdx.x] = z1[g * 512 + threadIdx.x];
  p[256 + threadIdx.x] = z1[g * 512 + 256 + threadIdx.x];
  __syncthreads();
  float acc = b[threadIdx.x];
#pragma unroll 8
  for (int k = 0; k < 512; ++k) acc = fmaf(p[k], W[k * 256 + threadIdx.x], acc);
  out[g * 256 + threadIdx.x] = fmaxf(acc, 0.f);
}

__global__ void mlp3_kernel(const float* __restrict__ z2, const float* __restrict__ W,
                            const float* __restrict__ b, float* __restrict__ out) {
  int g = blockIdx.x;
  int lane = threadIdx.x;
  float acc[10];
#pragma unroll
  for (int o = 0; o < 10; ++o) acc[o] = 0.f;
  for (int k = lane; k < 256; k += 64) {
    float v = z2[g * 256 + k];
#pragma unroll
    for (int o = 0; o < 10; ++o) acc[o] = fmaf(v, W[k * 10 + o], acc[o]);
  }
#pragma unroll
  for (int o = 0; o < 10; ++o) {
    float s = acc[o];
    for (int d = 32; d > 0; d >>= 1) s += __shfl_down(s, d);
    if (lane == 0) out[g * 10 + o] = s + b[o];
  }
}

// ---------------- launch ----------------

extern "C" void kernel_launch(void* const* d_in, const int* in_sizes, int n_in,
                              void* d_out, int out_size, void* d_ws, size_t ws_size,
                              hipStream_t stream) {
  const float* x = (const float*)d_in[0];
  const int* ei = (const int*)d_in[1];
  const int* batch = (const int*)d_in[2];
  const float* fl_W = (const float*)d_in[3];
  const float* fl_b = (const float*)d_in[4];
  const float* conv1_W = (const float*)d_in[5];
  const float* conv1_b = (const float*)d_in[6];
  const float* tr1_W = (const float*)d_in[7];
  const float* tr1_b = (const float*)d_in[8];
  const float* bn1_g = (const float*)d_in[9];
  const float* bn1_b = (const float*)d_in[10];
  const float* convs_W = (const float*)d_in[11];
  const float* convs_b = (const float*)d_in[12];
  const float* trs_W = (const float*)d_in[13];
  const float* trs_b = (const float*)d_in[14];
  const float* bns_g = (const float*)d_in[15];
  const float* bns_b = (const float*)d_in[16];
  const float* l1_W = (const float*)d_in[17];
  const float* l1_b = (const float*)d_in[18];
  const float* l2_W = (const float*)d_in[19];
  const float* l2_b = (const float*)d_in[20];
  const float* l3_W = (const float*)d_in[21];
  const float* l3_b = (const float*)d_in[22];

  const int N = in_sizes[0] / 128;
  const int E = in_sizes[1] / 2;
  const int G = out_size / 10;
  const int NL = in_sizes[11] / (256 * 256);
  const int* src = ei;
  const int* dst = ei + E;

  char* ws = (char*)d_ws;
  size_t o = 0;
  auto alloc = [&](size_t bytes) -> char* {
    o = (o + 255) & ~(size_t)255;
    char* p = ws + o;
    o += bytes;
    return p;
  };
  u32* hA = (u32*)alloc((size_t)N * DD * 4);
  u32* hB = (u32*)alloc((size_t)N * DD * 4);
  float* dis = (float*)alloc((size_t)N * 4);
  int* cnt = (int*)alloc((size_t)N * 4);
  int* off = (int*)alloc((size_t)(N + 1) * 4);
  int* cursor = (int*)alloc((size_t)N * 4);
  int* bsum = (int*)alloc(64 * 4);
  int* csr = (int*)alloc((size_t)E * 4);
  float* bnsums = (float*)alloc((size_t)(1 + NL) * 512 * 4);
  float* scalev = (float*)alloc(256 * 4);
  float* shiftv = (float*)alloc(256 * 4);
  float* pooled = (float*)alloc((size_t)G * 256 * 4);
  float* z1 = (float*)alloc((size_t)G * 512 * 4);
  float* z2 = (float*)alloc((size_t)G * 256 * 4);
  u16* flHi = (u16*)alloc(128 * 256 * 2);
  u16* flLo = (u16*)alloc(128 * 256 * 2);
  u16* cvHi = (u16*)alloc((size_t)(1 + NL) * 256 * 256 * 2);
  u16* cvLo = (u16*)alloc((size_t)(1 + NL) * 256 * 256 * 2);
  u16* trHi = (u16*)alloc(256 * 256 * 2);
  u16* trLo = (u16*)alloc(256 * 256 * 2);
  float* trBias = (float*)alloc(256 * 4);

  dim3 b256(256);
  const int nblk = (N + 63) / 64;
  dim3 ggrid(nblk, 2);  // 64x128 blocks

  // CSR build
  zero_i32_kernel<<<(N + 255) / 256, b256, 0, stream>>>(cnt, N);
  count_kernel<<<(E + 255) / 256, b256, 0, stream>>>(dst, cnt, E);
  int nb = (N + 1023) / 1024;
  scan_block_kernel<<<nb, b256, 0, stream>>>(cnt, off, bsum, N);
  scan_partials_kernel<<<1, 64, 0, stream>>>(bsum, nb);
  finalize_kernel<<<(N + 255) / 256, b256, 0, stream>>>(off, bsum, cursor, cnt, dis, N, E);
  fill_kernel<<<(E + 255) / 256, b256, 0, stream>>>(src, dst, cursor, csr, E);

  // static weight splits (batched) + zero all BN slots once
  dim3 wgrid(256, 2 + NL);
  wsplit_all_kernel<<<wgrid, b256, 0, stream>>>(fl_W, conv1_W, convs_W, flHi, flLo, cvHi, cvLo);
  zero_f32_kernel<<<(int)(((1 + NL) * 512 + 255) / 256), b256, 0, stream>>>(bnsums, (1 + NL) * 512);

  // fl: x @ fl_W + fl_b -> hA; conv1: hA @ Wc1 -> hB (m1)
  gemm_mfma_kernel<128, false, true><<<ggrid, b256, 0, stream>>>(x, flHi, flLo, fl_b, hA, N);
  gemm_mfma_kernel<256, false, false><<<ggrid, b256, 0, stream>>>(hA, cvHi, cvLo, nullptr, hB, N);

  for (int L = 0; L < 1 + NL; ++L) {
    const float* bc = (L == 0) ? conv1_b : convs_b + (size_t)(L - 1) * 256;
    const float* gg = (L == 0) ? bn1_g : bns_g + (size_t)(L - 1) * 256;
    const float* gb = (L == 0) ? bn1_b : bns_b + (size_t)(L - 1) * 256;
    const float* Wt = (L == 0) ? tr1_W : trs_W + (size_t)(L - 1) * 256 * 256;
    const float* bt = (L == 0) ? tr1_b : trs_b + (size_t)(L - 1) * 256;
    float* slot = bnsums + (size_t)L * 512;

    // gather m (hB) -> h_agg (hA)
    gather_kernel<<<(N + 3) / 4, b256, 0, stream>>>(hB, off, csr, dis, bc, hA, N);
    bn_partial_kernel<<<1024, b256, 0, stream>>>(hA, slot, N);
    bn_finalize_kernel<<<1, b256, 0, stream>>>(slot, gg, gb, scalev, shiftv, 1.0f / (float)N);
    wsplit_fold_kernel<<<256, b256, 0, stream>>>(Wt, scalev, shiftv, bt, trHi, trLo, trBias);
    // tr: h_agg (hA) -> hB (m dead)
    gemm_mfma_kernel<256, true, false><<<ggrid, b256, 0, stream>>>(hA, trHi, trLo, trBias, hB, N);
    if (L < NL) {
      // conv(L+1): hB -> hA, then swap so m lives in hB
      gemm_mfma_kernel<256, false, false><<<ggrid, b256, 0, stream>>>(
          hB, cvHi + (size_t)(L + 1) * 65536, cvLo + (size_t)(L + 1) * 65536, nullptr, hA, N);
      u32* t = hA; hA = hB; hB = t;
    }
  }

  pool_kernel<<<G, b256, 0, stream>>>(hB, batch, pooled, N);
  dim3 m1grid(G, 2);
  mlp1_kernel<<<m1grid, b256, 0, stream>>>(pooled, l1_W, l1_b, z1);
  mlp2_kernel<<<G, b256, 0, stream>>>(z1, l2_W, l2_b, z2);
  mlp3_kernel<<<G, 64, 0, stream>>>(z2, l3_W, l3_b, (float*)d_out);
}

// Round 6
// 1727.659 us; speedup vs baseline: 1.1450x; 1.1450x over previous
//
#include <hip/hip_runtime.h>

#define DD 256

typedef unsigned short u16;
typedef unsigned int u32;
using bf16x8 = __attribute__((ext_vector_type(8))) short;  // 8 bf16 (4 VGPRs)
using f32x4  = __attribute__((ext_vector_type(4))) float;

// ---- bfx2 helpers: uint32 = hi_bf16 (bits 15:0) | lo_bf16 (bits 31:16) ----

__device__ __forceinline__ u32 f2bfx2(float v) {
  u32 b = __float_as_uint(v);
  u32 hi = (b + 0x7fffu + ((b >> 16) & 1u)) >> 16;  // RNE bf16
  float hf = __uint_as_float(hi << 16);
  float lof = v - hf;
  u32 b2 = __float_as_uint(lof);
  u32 lo = (b2 + 0x7fffu + ((b2 >> 16) & 1u)) >> 16;
  return hi | (lo << 16);
}

__device__ __forceinline__ float bfx2_to_f(u32 e) {
  return __uint_as_float(e << 16) + __uint_as_float(e & 0xffff0000u);
}

__device__ __forceinline__ bf16x8 as_bf16x8(uint4 u) {
  union { uint4 u; bf16x8 v; } c;
  c.u = u;
  return c.v;
}

// deinterleave 8 packed bfx2 (a,b) into hi-plane / lo-plane bf16x8
__device__ __forceinline__ void unpack8(uint4 a, uint4 b, bf16x8& hi, bf16x8& lo) {
  union { u32 w[4]; bf16x8 v; } H, L;
  H.w[0] = __builtin_amdgcn_perm(a.y, a.x, 0x05040100u);
  L.w[0] = __builtin_amdgcn_perm(a.y, a.x, 0x07060302u);
  H.w[1] = __builtin_amdgcn_perm(a.w, a.z, 0x05040100u);
  L.w[1] = __builtin_amdgcn_perm(a.w, a.z, 0x07060302u);
  H.w[2] = __builtin_amdgcn_perm(b.y, b.x, 0x05040100u);
  L.w[2] = __builtin_amdgcn_perm(b.y, b.x, 0x07060302u);
  H.w[3] = __builtin_amdgcn_perm(b.w, b.z, 0x05040100u);
  L.w[3] = __builtin_amdgcn_perm(b.w, b.z, 0x07060302u);
  hi = H.v;
  lo = L.v;
}

// ---------------- CSR build ----------------

__global__ void zero_i32_kernel(int* p, int n) {
  int i = blockIdx.x * 256 + threadIdx.x;
  if (i < n) p[i] = 0;
}

__global__ void zero_f32_kernel(float* p, int n) {
  int i = blockIdx.x * 256 + threadIdx.x;
  if (i < n) p[i] = 0.f;
}

__global__ void count_kernel(const int* __restrict__ dst, int* __restrict__ cnt, int e) {
  int i = blockIdx.x * 256 + threadIdx.x;
  if (i < e) atomicAdd(&cnt[dst[i]], 1);
}

__global__ void scan_block_kernel(const int* __restrict__ cnt, int* __restrict__ out,
                                  int* __restrict__ bsum, int n) {
  __shared__ int sh[256];
  int tid = threadIdx.x;
  int base = blockIdx.x * 1024 + tid * 4;
  int v0 = (base + 0 < n) ? cnt[base + 0] : 0;
  int v1 = (base + 1 < n) ? cnt[base + 1] : 0;
  int v2 = (base + 2 < n) ? cnt[base + 2] : 0;
  int v3 = (base + 3 < n) ? cnt[base + 3] : 0;
  int s = v0 + v1 + v2 + v3;
  sh[tid] = s;
  __syncthreads();
  for (int d = 1; d < 256; d <<= 1) {
    int t = (tid >= d) ? sh[tid - d] : 0;
    __syncthreads();
    sh[tid] += t;
    __syncthreads();
  }
  int excl = sh[tid] - s;
  if (base + 0 < n) out[base + 0] = excl;
  excl += v0;
  if (base + 1 < n) out[base + 1] = excl;
  excl += v1;
  if (base + 2 < n) out[base + 2] = excl;
  excl += v2;
  if (base + 3 < n) out[base + 3] = excl;
  if (tid == 255) bsum[blockIdx.x] = sh[255];
}

__global__ void scan_partials_kernel(int* bsum, int nb) {
  if (threadIdx.x == 0 && blockIdx.x == 0) {
    int acc = 0;
    for (int i = 0; i < nb; ++i) { int t = bsum[i]; bsum[i] = acc; acc += t; }
  }
}

__global__ void finalize_kernel(int* __restrict__ off, const int* __restrict__ bsum,
                                int* __restrict__ cursor, const int* __restrict__ cnt,
                                float* __restrict__ dis, int n, int e) {
  int i = blockIdx.x * 256 + threadIdx.x;
  if (i < n) {
    int o = off[i] + bsum[i >> 10];
    off[i] = o;
    cursor[i] = o;
    dis[i] = rsqrtf((float)(cnt[i] + 1));  // deg includes self-loop
  }
  if (i == 0 && blockIdx.x == 0) off[n] = e;
}

__global__ void fill_kernel(const int* __restrict__ src, const int* __restrict__ dst,
                            int* __restrict__ cursor, int* __restrict__ csr_src, int e) {
  int i = blockIdx.x * 256 + threadIdx.x;
  if (i < e) {
    int d = dst[i];
    int p = atomicAdd(&cursor[d], 1);
    csr_src[p] = src[i];
  }
}

// ---------------- weight prep ----------------

__global__ void wsplit_all_kernel(const float* __restrict__ fl_W, const float* __restrict__ conv1_W,
                                  const float* __restrict__ convs_W, u16* __restrict__ flHi,
                                  u16* __restrict__ flLo, u16* __restrict__ cvHi,
                                  u16* __restrict__ cvLo) {
  int j = blockIdx.x;   // output column
  int m = blockIdx.y;   // matrix id
  int k = threadIdx.x;  // input row
  if (m == 0) {
    if (k < 128) {
      u32 p = f2bfx2(fl_W[(size_t)k * 256 + j]);
      flHi[(size_t)j * 128 + k] = (u16)(p & 0xffffu);
      flLo[(size_t)j * 128 + k] = (u16)(p >> 16);
    }
  } else {
    int c = m - 1;
    const float* W = (c == 0) ? conv1_W : convs_W + (size_t)(c - 1) * 65536;
    u32 p = f2bfx2(W[(size_t)k * 256 + j]);
    cvHi[(size_t)c * 65536 + (size_t)j * 256 + k] = (u16)(p & 0xffffu);
    cvLo[(size_t)c * 65536 + (size_t)j * 256 + k] = (u16)(p >> 16);
  }
}

// tr prep: W' = diag(scale)@Wt split/transposed; bias_out = bt + shift@Wt. grid 256.
__global__ void wsplit_fold_kernel(const float* __restrict__ W, const float* __restrict__ scale,
                                   const float* __restrict__ shift, const float* __restrict__ bt,
                                   u16* __restrict__ WhiT, u16* __restrict__ WloT,
                                   float* __restrict__ bias_out) {
  __shared__ float red[256];
  int j = blockIdx.x;
  int k = threadIdx.x;
  float w = W[(size_t)k * 256 + j];
  u32 p = f2bfx2(w * scale[k]);
  WhiT[(size_t)j * 256 + k] = (u16)(p & 0xffffu);
  WloT[(size_t)j * 256 + k] = (u16)(p >> 16);
  red[k] = shift[k] * w;
  __syncthreads();
  for (int d = 128; d > 0; d >>= 1) {
    if (k < d) red[k] += red[k + d];
    __syncthreads();
  }
  if (k == 0) bias_out[j] = bt[j] + red[0];
}

// ---------------- MFMA GEMM (split bf16 ~ fp32 precision) ----------------
// Block = 32 rows x 256 cols, 4 waves; wave owns 64 cols -> acc 2x4 (32 f32).
// Small acc + no B double-buffer keeps VGPR <= 128 -> 4 waves/SIMD.

#define SWZ(row, byteoff) ((byteoff) ^ (((row) & 7) << 4))

template <int K, bool RELU, bool AF32>
__global__ __launch_bounds__(256, 4) void gemm_mfma_kernel(
    const void* __restrict__ Av, const u16* __restrict__ WhiT, const u16* __restrict__ WloT,
    const float* __restrict__ bias, u32* __restrict__ C, int nrows) {
  const int tid = threadIdx.x;
  const int lane = tid & 63;
  const int wave = tid >> 6;
  const int row0 = blockIdx.x * 32;
  const int q = lane >> 4;
  const int r16 = lane & 15;

  int aOff[2];
#pragma unroll
  for (int i = 0; i < 2; ++i) {
    int row = row0 + i * 16 + r16;
    if (row > nrows - 1) row = nrows - 1;  // clamp; masked at epilogue
    aOff[i] = row * K + q * 8;
  }
  int bOff[4];
#pragma unroll
  for (int r = 0; r < 4; ++r) bOff[r] = (wave * 64 + r * 16 + r16) * K + q * 8;

  f32x4 acc[2][4];
#pragma unroll
  for (int i = 0; i < 2; ++i)
#pragma unroll
    for (int r = 0; r < 4; ++r) acc[i][r] = (f32x4){0.f, 0.f, 0.f, 0.f};

  auto loadA = [&](int k0, uint4 (&dst)[2][2]) {
#pragma unroll
    for (int i = 0; i < 2; ++i) {
      if (AF32) {
        const float* ap = (const float*)Av + aOff[i] + k0;
        float4 f0 = *(const float4*)ap;
        float4 f1 = *(const float4*)(ap + 4);
        dst[i][0] = make_uint4(f2bfx2(f0.x), f2bfx2(f0.y), f2bfx2(f0.z), f2bfx2(f0.w));
        dst[i][1] = make_uint4(f2bfx2(f1.x), f2bfx2(f1.y), f2bfx2(f1.z), f2bfx2(f1.w));
      } else {
        const u32* ap = (const u32*)Av + aOff[i] + k0;
        dst[i][0] = *(const uint4*)ap;
        dst[i][1] = *(const uint4*)(ap + 4);
      }
    }
  };

  uint4 curA[2][2];
  loadA(0, curA);

#pragma unroll
  for (int k0 = 0; k0 < K; k0 += 32) {
    uint4 nxtA[2][2];
    if (k0 + 32 < K) loadA(k0 + 32, nxtA);
    bf16x8 ah[2], al[2];
    unpack8(curA[0][0], curA[0][1], ah[0], al[0]);
    unpack8(curA[1][0], curA[1][1], ah[1], al[1]);
#pragma unroll
    for (int r = 0; r < 4; ++r) {
      bf16x8 bh = as_bf16x8(*(const uint4*)(WhiT + bOff[r] + k0));
      bf16x8 bl = as_bf16x8(*(const uint4*)(WloT + bOff[r] + k0));
#pragma unroll
      for (int i = 0; i < 2; ++i) {
        acc[i][r] = __builtin_amdgcn_mfma_f32_16x16x32_bf16(ah[i], bh, acc[i][r], 0, 0, 0);
        acc[i][r] = __builtin_amdgcn_mfma_f32_16x16x32_bf16(al[i], bh, acc[i][r], 0, 0, 0);
        acc[i][r] = __builtin_amdgcn_mfma_f32_16x16x32_bf16(ah[i], bl, acc[i][r], 0, 0, 0);
      }
    }
    if (k0 + 32 < K) {
#pragma unroll
      for (int i = 0; i < 2; ++i) {
        curA[i][0] = nxtA[i][0];
        curA[i][1] = nxtA[i][1];
      }
    }
  }

  // epilogue: C/D layout col=lane&15, row=(lane>>4)*4+reg
#pragma unroll
  for (int r = 0; r < 4; ++r) {
    int col = wave * 64 + r * 16 + r16;
    float bv = bias ? bias[col] : 0.f;
#pragma unroll
    for (int i = 0; i < 2; ++i) {
#pragma unroll
      for (int g = 0; g < 4; ++g) {
        int row = row0 + i * 16 + q * 4 + g;
        if (row < nrows) {
          float v = acc[i][r][g] + bv;
          if (RELU) v = fmaxf(v, 0.f);
          C[(size_t)row * 256 + col] = f2bfx2(v);
        }
      }
    }
  }
}

// fused: T = act1(A @ W1 + bias1) kept in 32KB swizzled LDS, C = T @ W2.
template <int K1, bool RELU1, bool AF32>
__global__ __launch_bounds__(256, 4) void fused_gemm_kernel(
    const void* __restrict__ Av, const u16* __restrict__ W1h, const u16* __restrict__ W1l,
    const float* __restrict__ bias1, const u16* __restrict__ W2h, const u16* __restrict__ W2l,
    u32* __restrict__ C, int nrows) {
  __shared__ u32 T[32 * 256];  // 32KB swizzled bfx2 tile
  const int tid = threadIdx.x;
  const int lane = tid & 63;
  const int wave = tid >> 6;
  const int row0 = blockIdx.x * 32;
  const int q = lane >> 4;
  const int r16 = lane & 15;

  // ---------- phase 1: A @ W1 ----------
  int aOff[2];
#pragma unroll
  for (int i = 0; i < 2; ++i) {
    int row = row0 + i * 16 + r16;
    if (row > nrows - 1) row = nrows - 1;
    aOff[i] = row * K1 + q * 8;
  }
  int bOff1[4];
#pragma unroll
  for (int r = 0; r < 4; ++r) bOff1[r] = (wave * 64 + r * 16 + r16) * K1 + q * 8;

  f32x4 acc[2][4];
#pragma unroll
  for (int i = 0; i < 2; ++i)
#pragma unroll
    for (int r = 0; r < 4; ++r) acc[i][r] = (f32x4){0.f, 0.f, 0.f, 0.f};

  auto loadA = [&](int k0, uint4 (&dst)[2][2]) {
#pragma unroll
    for (int i = 0; i < 2; ++i) {
      if (AF32) {
        const float* ap = (const float*)Av + aOff[i] + k0;
        float4 f0 = *(const float4*)ap;
        float4 f1 = *(const float4*)(ap + 4);
        dst[i][0] = make_uint4(f2bfx2(f0.x), f2bfx2(f0.y), f2bfx2(f0.z), f2bfx2(f0.w));
        dst[i][1] = make_uint4(f2bfx2(f1.x), f2bfx2(f1.y), f2bfx2(f1.z), f2bfx2(f1.w));
      } else {
        const u32* ap = (const u32*)Av + aOff[i] + k0;
        dst[i][0] = *(const uint4*)ap;
        dst[i][1] = *(const uint4*)(ap + 4);
      }
    }
  };

  {
    uint4 curA[2][2];
    loadA(0, curA);
#pragma unroll
    for (int k0 = 0; k0 < K1; k0 += 32) {
      uint4 nxtA[2][2];
      if (k0 + 32 < K1) loadA(k0 + 32, nxtA);
      bf16x8 ah[2], al[2];
      unpack8(curA[0][0], curA[0][1], ah[0], al[0]);
      unpack8(curA[1][0], curA[1][1], ah[1], al[1]);
#pragma unroll
      for (int r = 0; r < 4; ++r) {
        bf16x8 bh = as_bf16x8(*(const uint4*)(W1h + bOff1[r] + k0));
        bf16x8 bl = as_bf16x8(*(const uint4*)(W1l + bOff1[r] + k0));
#pragma unroll
        for (int i = 0; i < 2; ++i) {
          acc[i][r] = __builtin_amdgcn_mfma_f32_16x16x32_bf16(ah[i], bh, acc[i][r], 0, 0, 0);
          acc[i][r] = __builtin_amdgcn_mfma_f32_16x16x32_bf16(al[i], bh, acc[i][r], 0, 0, 0);
          acc[i][r] = __builtin_amdgcn_mfma_f32_16x16x32_bf16(ah[i], bl, acc[i][r], 0, 0, 0);
        }
      }
      if (k0 + 32 < K1) {
#pragma unroll
        for (int i = 0; i < 2; ++i) {
          curA[i][0] = nxtA[i][0];
          curA[i][1] = nxtA[i][1];
        }
      }
    }
  }

  // epilogue 1 -> swizzled LDS tile (local rows 0..31)
#pragma unroll
  for (int r = 0; r < 4; ++r) {
    int col = wave * 64 + r * 16 + r16;
    float bv = bias1[col];
#pragma unroll
    for (int i = 0; i < 2; ++i) {
#pragma unroll
      for (int g = 0; g < 4; ++g) {
        int row = i * 16 + q * 4 + g;
        float v = acc[i][r][g] + bv;
        if (RELU1) v = fmaxf(v, 0.f);
        *(u32*)((char*)T + SWZ(row, (row * 256 + col) * 4)) = f2bfx2(v);
      }
    }
  }
  __syncthreads();

  // ---------- phase 2: T @ W2 ----------
#pragma unroll
  for (int i = 0; i < 2; ++i)
#pragma unroll
    for (int r = 0; r < 4; ++r) acc[i][r] = (f32x4){0.f, 0.f, 0.f, 0.f};

  int bOff2[4];
#pragma unroll
  for (int r = 0; r < 4; ++r) bOff2[r] = (wave * 64 + r * 16 + r16) * 256 + q * 8;

#pragma unroll
  for (int k0 = 0; k0 < 256; k0 += 32) {
    bf16x8 ah[2], al[2];
#pragma unroll
    for (int i = 0; i < 2; ++i) {
      int row = i * 16 + r16;
      int base = row * 1024 + k0 * 4 + q * 32;
      uint4 a0 = *(const uint4*)((char*)T + SWZ(row, base));
      uint4 a1 = *(const uint4*)((char*)T + SWZ(row, base + 16));
      unpack8(a0, a1, ah[i], al[i]);
    }
#pragma unroll
    for (int r = 0; r < 4; ++r) {
      bf16x8 bh = as_bf16x8(*(const uint4*)(W2h + bOff2[r] + k0));
      bf16x8 bl = as_bf16x8(*(const uint4*)(W2l + bOff2[r] + k0));
#pragma unroll
      for (int i = 0; i < 2; ++i) {
        acc[i][r] = __builtin_amdgcn_mfma_f32_16x16x32_bf16(ah[i], bh, acc[i][r], 0, 0, 0);
        acc[i][r] = __builtin_amdgcn_mfma_f32_16x16x32_bf16(al[i], bh, acc[i][r], 0, 0, 0);
        acc[i][r] = __builtin_amdgcn_mfma_f32_16x16x32_bf16(ah[i], bl, acc[i][r], 0, 0, 0);
      }
    }
  }

  // epilogue 2: write m (no bias/act; conv bias applied in gather)
#pragma unroll
  for (int r = 0; r < 4; ++r) {
    int col = wave * 64 + r * 16 + r16;
#pragma unroll
    for (int i = 0; i < 2; ++i) {
#pragma unroll
      for (int g = 0; g < 4; ++g) {
        int row = row0 + i * 16 + q * 4 + g;
        if (row < nrows) C[(size_t)row * 256 + col] = f2bfx2(acc[i][r][g]);
      }
    }
  }
}

// ---------------- GCN gather (bfx2 in/out), 4-edge unroll ----------------

__global__ __launch_bounds__(256) void gather_kernel(
    const u32* __restrict__ m, const int* __restrict__ off,
    const int* __restrict__ csr_src, const float* __restrict__ dis,
    const float* __restrict__ bias, u32* __restrict__ out, int n) {
  int node = blockIdx.x * 4 + (threadIdx.x >> 6);
  if (node >= n) return;
  int lane = threadIdx.x & 63;
  float di = dis[node];
  uint4 v = *(const uint4*)(m + (size_t)node * DD + lane * 4);
  float w = di * di;
  float ax = w * bfx2_to_f(v.x), ay = w * bfx2_to_f(v.y);
  float az = w * bfx2_to_f(v.z), aw = w * bfx2_to_f(v.w);
  int e0 = off[node], e1 = off[node + 1];
  int e = e0;
  for (; e + 3 < e1; e += 4) {
    int s0 = csr_src[e], s1 = csr_src[e + 1], s2 = csr_src[e + 2], s3 = csr_src[e + 3];
    float w0 = dis[s0] * di, w1 = dis[s1] * di, w2 = dis[s2] * di, w3 = dis[s3] * di;
    uint4 u0 = *(const uint4*)(m + (size_t)s0 * DD + lane * 4);
    uint4 u1 = *(const uint4*)(m + (size_t)s1 * DD + lane * 4);
    uint4 u2 = *(const uint4*)(m + (size_t)s2 * DD + lane * 4);
    uint4 u3 = *(const uint4*)(m + (size_t)s3 * DD + lane * 4);
    ax = fmaf(w0, bfx2_to_f(u0.x), ax); ay = fmaf(w0, bfx2_to_f(u0.y), ay);
    az = fmaf(w0, bfx2_to_f(u0.z), az); aw = fmaf(w0, bfx2_to_f(u0.w), aw);
    ax = fmaf(w1, bfx2_to_f(u1.x), ax); ay = fmaf(w1, bfx2_to_f(u1.y), ay);
    az = fmaf(w1, bfx2_to_f(u1.z), az); aw = fmaf(w1, bfx2_to_f(u1.w), aw);
    ax = fmaf(w2, bfx2_to_f(u2.x), ax); ay = fmaf(w2, bfx2_to_f(u2.y), ay);
    az = fmaf(w2, bfx2_to_f(u2.z), az); aw = fmaf(w2, bfx2_to_f(u2.w), aw);
    ax = fmaf(w3, bfx2_to_f(u3.x), ax); ay = fmaf(w3, bfx2_to_f(u3.y), ay);
    az = fmaf(w3, bfx2_to_f(u3.z), az); aw = fmaf(w3, bfx2_to_f(u3.w), aw);
  }
  for (; e < e1; ++e) {
    int s0 = csr_src[e];
    float w0 = dis[s0] * di;
    uint4 u0 = *(const uint4*)(m + (size_t)s0 * DD + lane * 4);
    ax = fmaf(w0, bfx2_to_f(u0.x), ax); ay = fmaf(w0, bfx2_to_f(u0.y), ay);
    az = fmaf(w0, bfx2_to_f(u0.z), az); aw = fmaf(w0, bfx2_to_f(u0.w), aw);
  }
  float4 bb = *(const float4*)(bias + lane * 4);
  uint4 oo;
  oo.x = f2bfx2(fmaxf(ax + bb.x, 0.f));
  oo.y = f2bfx2(fmaxf(ay + bb.y, 0.f));
  oo.z = f2bfx2(fmaxf(az + bb.z, 0.f));
  oo.w = f2bfx2(fmaxf(aw + bb.w, 0.f));
  *(uint4*)(out + (size_t)node * DD + lane * 4) = oo;
}

// ---------------- BatchNorm stats ----------------

__global__ void bn_partial_kernel(const u32* __restrict__ h, float* __restrict__ sums, int n) {
  int c = threadIdx.x;
  float s = 0.f, q = 0.f;
  for (int r = blockIdx.x; r < n; r += gridDim.x) {
    float v = bfx2_to_f(h[(size_t)r * DD + c]);
    s += v;
    q += v * v;
  }
  atomicAdd(&sums[c], s);
  atomicAdd(&sums[DD + c], q);
}

__global__ void bn_finalize_kernel(const float* __restrict__ sums, const float* __restrict__ g,
                                   const float* __restrict__ b, float* __restrict__ scale,
                                   float* __restrict__ shift, float inv_n) {
  int c = threadIdx.x;
  float mu = sums[c] * inv_n;
  float var = sums[DD + c] * inv_n - mu * mu;
  float inv = rsqrtf(var + 1e-5f);
  float sc = g[c] * inv;
  scale[c] = sc;
  shift[c] = b[c] - mu * sc;
}

// ---------------- global mean pool ----------------

__global__ void pool_kernel(const u32* __restrict__ h, const int* __restrict__ batch,
                            float* __restrict__ pooled, int n) {
  int g = blockIdx.x;
  int c = threadIdx.x;
  int lo = 0, hi = n;
  while (lo < hi) { int mid = (lo + hi) >> 1; if (batch[mid] < g) lo = mid + 1; else hi = mid; }
  int start = lo;
  hi = n;
  while (lo < hi) { int mid = (lo + hi) >> 1; if (batch[mid] <= g) lo = mid + 1; else hi = mid; }
  int end = lo;
  float a0 = 0.f, a1 = 0.f, a2 = 0.f, a3 = 0.f;
  int r = start;
  for (; r + 3 < end; r += 4) {
    a0 += bfx2_to_f(h[(size_t)(r + 0) * DD + c]);
    a1 += bfx2_to_f(h[(size_t)(r + 1) * DD + c]);
    a2 += bfx2_to_f(h[(size_t)(r + 2) * DD + c]);
    a3 += bfx2_to_f(h[(size_t)(r + 3) * DD + c]);
  }
  for (; r < end; ++r) a0 += bfx2_to_f(h[(size_t)r * DD + c]);
  float s = (a0 + a1) + (a2 + a3);
  int cg = end - start;
  pooled[g * DD + c] = s / (float)(cg > 1 ? cg : 1);
}

// ---------------- MLP head ----------------

__global__ void mlp1_kernel(const float* __restrict__ pooled, const float* __restrict__ W,
                            const float* __restrict__ b, float* __restrict__ out) {
  __shared__ float p[256];
  int g = blockIdx.x;
  int j = blockIdx.y * 256 + threadIdx.x;
  p[threadIdx.x] = pooled[g * 256 + threadIdx.x];
  __syncthreads();
  float acc = b[j];
#pragma unroll 8
  for (int k = 0; k < 512; ++k) acc = fmaf(p[k & 255], W[k * 512 + j], acc);
  out[g * 512 + j] = fmaxf(acc, 0.f);
}

__global__ void mlp2_kernel(const float* __restrict__ z1, const float* __restrict__ W,
                            const float* __restrict__ b, float* __restrict__ out) {
  __shared__ float p[512];
  int g = blockIdx.x;
  p[threadIdx.x] = z1[g * 512 + threadIdx.x];
  p[256 + threadIdx.x] = z1[g * 512 + 256 + threadIdx.x];
  __syncthreads();
  float acc = b[threadIdx.x];
#pragma unroll 8
  for (int k = 0; k < 512; ++k) acc = fmaf(p[k], W[k * 256 + threadIdx.x], acc);
  out[g * 256 + threadIdx.x] = fmaxf(acc, 0.f);
}

__global__ void mlp3_kernel(const float* __restrict__ z2, const float* __restrict__ W,
                            const float* __restrict__ b, float* __restrict__ out) {
  int g = blockIdx.x;
  int lane = threadIdx.x;
  float acc[10];
#pragma unroll
  for (int o = 0; o < 10; ++o) acc[o] = 0.f;
  for (int k = lane; k < 256; k += 64) {
    float v = z2[g * 256 + k];
#pragma unroll
    for (int o = 0; o < 10; ++o) acc[o] = fmaf(v, W[k * 10 + o], acc[o]);
  }
#pragma unroll
  for (int o = 0; o < 10; ++o) {
    float s = acc[o];
    for (int d = 32; d > 0; d >>= 1) s += __shfl_down(s, d);
    if (lane == 0) out[g * 10 + o] = s + b[o];
  }
}

// ---------------- launch ----------------

extern "C" void kernel_launch(void* const* d_in, const int* in_sizes, int n_in,
                              void* d_out, int out_size, void* d_ws, size_t ws_size,
                              hipStream_t stream) {
  const float* x = (const float*)d_in[0];
  const int* ei = (const int*)d_in[1];
  const int* batch = (const int*)d_in[2];
  const float* fl_W = (const float*)d_in[3];
  const float* fl_b = (const float*)d_in[4];
  const float* conv1_W = (const float*)d_in[5];
  const float* conv1_b = (const float*)d_in[6];
  const float* tr1_W = (const float*)d_in[7];
  const float* tr1_b = (const float*)d_in[8];
  const float* bn1_g = (const float*)d_in[9];
  const float* bn1_b = (const float*)d_in[10];
  const float* convs_W = (const float*)d_in[11];
  const float* convs_b = (const float*)d_in[12];
  const float* trs_W = (const float*)d_in[13];
  const float* trs_b = (const float*)d_in[14];
  const float* bns_g = (const float*)d_in[15];
  const float* bns_b = (const float*)d_in[16];
  const float* l1_W = (const float*)d_in[17];
  const float* l1_b = (const float*)d_in[18];
  const float* l2_W = (const float*)d_in[19];
  const float* l2_b = (const float*)d_in[20];
  const float* l3_W = (const float*)d_in[21];
  const float* l3_b = (const float*)d_in[22];

  const int N = in_sizes[0] / 128;
  const int E = in_sizes[1] / 2;
  const int G = out_size / 10;
  const int NL = in_sizes[11] / (256 * 256);
  const int* src = ei;
  const int* dst = ei + E;

  char* ws = (char*)d_ws;
  size_t o = 0;
  auto alloc = [&](size_t bytes) -> char* {
    o = (o + 255) & ~(size_t)255;
    char* p = ws + o;
    o += bytes;
    return p;
  };
  u32* hA = (u32*)alloc((size_t)N * DD * 4);   // h_agg (gather out)
  u32* hB = (u32*)alloc((size_t)N * DD * 4);   // m (conv out) / final h
  float* dis = (float*)alloc((size_t)N * 4);
  int* cnt = (int*)alloc((size_t)N * 4);
  int* off = (int*)alloc((size_t)(N + 1) * 4);
  int* cursor = (int*)alloc((size_t)N * 4);
  int* bsum = (int*)alloc(64 * 4);
  int* csr = (int*)alloc((size_t)E * 4);
  float* bnsums = (float*)alloc((size_t)(1 + NL) * 512 * 4);
  float* scalev = (float*)alloc(256 * 4);
  float* shiftv = (float*)alloc(256 * 4);
  float* pooled = (float*)alloc((size_t)G * 256 * 4);
  float* z1 = (float*)alloc((size_t)G * 512 * 4);
  float* z2 = (float*)alloc((size_t)G * 256 * 4);
  u16* flHi = (u16*)alloc(128 * 256 * 2);
  u16* flLo = (u16*)alloc(128 * 256 * 2);
  u16* cvHi = (u16*)alloc((size_t)(1 + NL) * 256 * 256 * 2);
  u16* cvLo = (u16*)alloc((size_t)(1 + NL) * 256 * 256 * 2);
  u16* trHi = (u16*)alloc(256 * 256 * 2);
  u16* trLo = (u16*)alloc(256 * 256 * 2);
  float* trBias = (float*)alloc(256 * 4);

  dim3 b256(256);
  const int nblk = (N + 31) / 32;  // 32-row blocks

  // CSR build
  zero_i32_kernel<<<(N + 255) / 256, b256, 0, stream>>>(cnt, N);
  count_kernel<<<(E + 255) / 256, b256, 0, stream>>>(dst, cnt, E);
  int nb = (N + 1023) / 1024;
  scan_block_kernel<<<nb, b256, 0, stream>>>(cnt, off, bsum, N);
  scan_partials_kernel<<<1, 64, 0, stream>>>(bsum, nb);
  finalize_kernel<<<(N + 255) / 256, b256, 0, stream>>>(off, bsum, cursor, cnt, dis, N, E);
  fill_kernel<<<(E + 255) / 256, b256, 0, stream>>>(src, dst, cursor, csr, E);

  // static weight splits (batched) + zero all BN slots once
  dim3 wgrid(256, 2 + NL);
  wsplit_all_kernel<<<wgrid, b256, 0, stream>>>(fl_W, conv1_W, convs_W, flHi, flLo, cvHi, cvLo);
  zero_f32_kernel<<<(int)(((1 + NL) * 512 + 255) / 256), b256, 0, stream>>>(bnsums, (1 + NL) * 512);

  // fused fl + conv1 -> m1 (hB)
  fused_gemm_kernel<128, false, true><<<nblk, b256, 0, stream>>>(x, flHi, flLo, fl_b, cvHi, cvLo,
                                                                 hB, N);

  for (int L = 0; L < 1 + NL; ++L) {
    const float* bc = (L == 0) ? conv1_b : convs_b + (size_t)(L - 1) * 256;
    const float* gg = (L == 0) ? bn1_g : bns_g + (size_t)(L - 1) * 256;
    const float* gb = (L == 0) ? bn1_b : bns_b + (size_t)(L - 1) * 256;
    const float* Wt = (L == 0) ? tr1_W : trs_W + (size_t)(L - 1) * 256 * 256;
    const float* bt = (L == 0) ? tr1_b : trs_b + (size_t)(L - 1) * 256;
    float* slot = bnsums + (size_t)L * 512;

    gather_kernel<<<(N + 3) / 4, b256, 0, stream>>>(hB, off, csr, dis, bc, hA, N);
    bn_partial_kernel<<<1024, b256, 0, stream>>>(hA, slot, N);
    bn_finalize_kernel<<<1, b256, 0, stream>>>(slot, gg, gb, scalev, shiftv, 1.0f / (float)N);
    wsplit_fold_kernel<<<256, b256, 0, stream>>>(Wt, scalev, shiftv, bt, trHi, trLo, trBias);
    if (L < NL) {
      // fused tr(L) + conv(L+1) -> m_{L+1}
      fused_gemm_kernel<256, true, false><<<nblk, b256, 0, stream>>>(
          hA, trHi, trLo, trBias, cvHi + (size_t)(L + 1) * 65536, cvLo + (size_t)(L + 1) * 65536,
          hB, N);
    } else {
      // final tr -> h
      gemm_mfma_kernel<256, true, false><<<nblk, b256, 0, stream>>>(hA, trHi, trLo, trBias, hB, N);
    }
  }

  pool_kernel<<<G, b256, 0, stream>>>(hB, batch, pooled, N);
  dim3 m1grid(G, 2);
  mlp1_kernel<<<m1grid, b256, 0, stream>>>(pooled, l1_W, l1_b, z1);
  mlp2_kernel<<<G, b256, 0, stream>>>(z1, l2_W, l2_b, z2);
  mlp3_kernel<<<G, 64, 0, stream>>>(z2, l3_W, l3_b, (float*)d_out);
}

// Round 7
// 1056.051 us; speedup vs baseline: 1.8732x; 1.6360x over previous
//
#include <hip/hip_runtime.h>

#define DD 256

typedef unsigned short u16;
typedef unsigned int u32;
using bf16x8 = __attribute__((ext_vector_type(8))) short;  // 8 bf16 (4 VGPRs)
using f32x4  = __attribute__((ext_vector_type(4))) float;

// ---- bfx2 helpers: uint32 = hi_bf16 (bits 15:0) | lo_bf16 (bits 31:16) ----

__device__ __forceinline__ u32 f2bfx2(float v) {
  u32 b = __float_as_uint(v);
  u32 hi = (b + 0x7fffu + ((b >> 16) & 1u)) >> 16;  // RNE bf16
  float hf = __uint_as_float(hi << 16);
  float lof = v - hf;
  u32 b2 = __float_as_uint(lof);
  u32 lo = (b2 + 0x7fffu + ((b2 >> 16) & 1u)) >> 16;
  return hi | (lo << 16);
}

__device__ __forceinline__ float bfx2_to_f(u32 e) {
  return __uint_as_float(e << 16) + __uint_as_float(e & 0xffff0000u);
}

// ---- fp16 helpers ----
__device__ __forceinline__ u16 f2h(float f) {
  _Float16 h = (_Float16)f;
  return __builtin_bit_cast(unsigned short, h);
}
__device__ __forceinline__ float h2f(u16 x) {
  return (float)__builtin_bit_cast(_Float16, x);
}

__device__ __forceinline__ bf16x8 as_bf16x8(uint4 u) {
  union { uint4 u; bf16x8 v; } c;
  c.u = u;
  return c.v;
}

// deinterleave 8 packed bfx2 (a,b) into hi-plane / lo-plane bf16x8
__device__ __forceinline__ void unpack8(uint4 a, uint4 b, bf16x8& hi, bf16x8& lo) {
  union { u32 w[4]; bf16x8 v; } H, L;
  H.w[0] = __builtin_amdgcn_perm(a.y, a.x, 0x05040100u);
  L.w[0] = __builtin_amdgcn_perm(a.y, a.x, 0x07060302u);
  H.w[1] = __builtin_amdgcn_perm(a.w, a.z, 0x05040100u);
  L.w[1] = __builtin_amdgcn_perm(a.w, a.z, 0x07060302u);
  H.w[2] = __builtin_amdgcn_perm(b.y, b.x, 0x05040100u);
  L.w[2] = __builtin_amdgcn_perm(b.y, b.x, 0x07060302u);
  H.w[3] = __builtin_amdgcn_perm(b.w, b.z, 0x05040100u);
  L.w[3] = __builtin_amdgcn_perm(b.w, b.z, 0x07060302u);
  hi = H.v;
  lo = L.v;
}

// packed B-plane layout: fragment-contiguous. For (col,k):
//   w=col>>6, r=(col>>4)&3, c16=col&15, kc=k>>5, q=(k>>3)&3, j=k&7
//   off = ((kc*4+w)*4+r)*512 + (q*16+c16)*8 + j
// -> a wave's fragment load (lane = q*16+c16, 8 u16 each) is 1KB contiguous.
__device__ __forceinline__ int packoff(int col, int k) {
  int w = col >> 6, r = (col >> 4) & 3, c16 = col & 15;
  int kc = k >> 5, q = (k >> 3) & 3, j = k & 7;
  return ((kc * 4 + w) * 4 + r) * 512 + (q * 16 + c16) * 8 + j;
}

// ---------------- CSR build ----------------

__global__ void zero_i32_kernel(int* p, int n) {
  int i = blockIdx.x * 256 + threadIdx.x;
  if (i < n) p[i] = 0;
}

__global__ void zero_f32_kernel(float* p, int n) {
  int i = blockIdx.x * 256 + threadIdx.x;
  if (i < n) p[i] = 0.f;
}

__global__ void count_kernel(const int* __restrict__ dst, int* __restrict__ cnt, int e) {
  int i = blockIdx.x * 256 + threadIdx.x;
  if (i < e) atomicAdd(&cnt[dst[i]], 1);
}

__global__ void scan_block_kernel(const int* __restrict__ cnt, int* __restrict__ out,
                                  int* __restrict__ bsum, int n) {
  __shared__ int sh[256];
  int tid = threadIdx.x;
  int base = blockIdx.x * 1024 + tid * 4;
  int v0 = (base + 0 < n) ? cnt[base + 0] : 0;
  int v1 = (base + 1 < n) ? cnt[base + 1] : 0;
  int v2 = (base + 2 < n) ? cnt[base + 2] : 0;
  int v3 = (base + 3 < n) ? cnt[base + 3] : 0;
  int s = v0 + v1 + v2 + v3;
  sh[tid] = s;
  __syncthreads();
  for (int d = 1; d < 256; d <<= 1) {
    int t = (tid >= d) ? sh[tid - d] : 0;
    __syncthreads();
    sh[tid] += t;
    __syncthreads();
  }
  int excl = sh[tid] - s;
  if (base + 0 < n) out[base + 0] = excl;
  excl += v0;
  if (base + 1 < n) out[base + 1] = excl;
  excl += v1;
  if (base + 2 < n) out[base + 2] = excl;
  excl += v2;
  if (base + 3 < n) out[base + 3] = excl;
  if (tid == 255) bsum[blockIdx.x] = sh[255];
}

__global__ void scan_partials_kernel(int* bsum, int nb) {
  if (threadIdx.x == 0 && blockIdx.x == 0) {
    int acc = 0;
    for (int i = 0; i < nb; ++i) { int t = bsum[i]; bsum[i] = acc; acc += t; }
  }
}

__global__ void finalize_kernel(int* __restrict__ off, const int* __restrict__ bsum,
                                int* __restrict__ cursor, const int* __restrict__ cnt,
                                float* __restrict__ dis, int n, int e) {
  int i = blockIdx.x * 256 + threadIdx.x;
  if (i < n) {
    int o = off[i] + bsum[i >> 10];
    off[i] = o;
    cursor[i] = o;
    dis[i] = rsqrtf((float)(cnt[i] + 1));  // deg includes self-loop
  }
  if (i == 0 && blockIdx.x == 0) off[n] = e;
}

__global__ void fill_kernel(const int* __restrict__ src, const int* __restrict__ dst,
                            int* __restrict__ cursor, int* __restrict__ csr_src, int e) {
  int i = blockIdx.x * 256 + threadIdx.x;
  if (i < e) {
    int d = dst[i];
    int p = atomicAdd(&cursor[d], 1);
    csr_src[p] = src[i];
  }
}

// ---------------- weight prep (packed layout) ----------------
// grid (256, 2+NL): y=0 -> fl (K=128), y>=1 -> conv matrix y-1 (K=256).

__global__ void wsplit_all_kernel(const float* __restrict__ fl_W, const float* __restrict__ conv1_W,
                                  const float* __restrict__ convs_W, u16* __restrict__ flHi,
                                  u16* __restrict__ flLo, u16* __restrict__ cvHi,
                                  u16* __restrict__ cvLo) {
  int j = blockIdx.x;   // output column
  int m = blockIdx.y;   // matrix id
  int k = threadIdx.x;  // input row
  if (m == 0) {
    if (k < 128) {
      u32 p = f2bfx2(fl_W[(size_t)k * 256 + j]);
      int off = packoff(j, k);
      flHi[off] = (u16)(p & 0xffffu);
      flLo[off] = (u16)(p >> 16);
    }
  } else {
    int c = m - 1;
    const float* W = (c == 0) ? conv1_W : convs_W + (size_t)(c - 1) * 65536;
    u32 p = f2bfx2(W[(size_t)k * 256 + j]);
    size_t off = (size_t)c * 65536 + packoff(j, k);
    cvHi[off] = (u16)(p & 0xffffu);
    cvLo[off] = (u16)(p >> 16);
  }
}

// tr prep: W' = diag(scale)@Wt packed; bias_out = bt + shift@Wt. grid 256.
__global__ void wsplit_fold_kernel(const float* __restrict__ W, const float* __restrict__ scale,
                                   const float* __restrict__ shift, const float* __restrict__ bt,
                                   u16* __restrict__ WhiT, u16* __restrict__ WloT,
                                   float* __restrict__ bias_out) {
  __shared__ float red[256];
  int j = blockIdx.x;
  int k = threadIdx.x;
  float w = W[(size_t)k * 256 + j];
  u32 p = f2bfx2(w * scale[k]);
  int off = packoff(j, k);
  WhiT[off] = (u16)(p & 0xffffu);
  WloT[off] = (u16)(p >> 16);
  red[k] = shift[k] * w;
  __syncthreads();
  for (int d = 128; d > 0; d >>= 1) {
    if (k < d) red[k] += red[k + d];
    __syncthreads();
  }
  if (k == 0) bias_out[j] = bt[j] + red[0];
}

// ---------------- MFMA GEMM pieces ----------------
// Split product ah*bh + ah*bl + al*bh (fp32 acc) ~ fp32 precision.
// Block = 32 rows x 256 cols, 4 waves; wave owns 64 cols -> acc 2x4.
// B loads: packed layout -> 1KB coalesced per fragment; A+B double-buffered.

#define SWZ(row, byteoff) ((byteoff) ^ (((row) & 7) << 4))

// standalone: C(bfx2) = act(A @ W + bias)
template <int K, bool RELU, bool AF32>
__global__ __launch_bounds__(256, 3) void gemm_mfma_kernel(
    const void* __restrict__ Av, const u16* __restrict__ WhiT, const u16* __restrict__ WloT,
    const float* __restrict__ bias, u32* __restrict__ C, int nrows) {
  constexpr int NK = K / 32;
  const int tid = threadIdx.x;
  const int lane = tid & 63;
  const int wave = tid >> 6;
  const int row0 = blockIdx.x * 32;
  const int q = lane >> 4;
  const int r16 = lane & 15;

  int aOff[2];
#pragma unroll
  for (int i = 0; i < 2; ++i) {
    int row = row0 + i * 16 + r16;
    if (row > nrows - 1) row = nrows - 1;  // clamp; masked at epilogue
    aOff[i] = row * K + q * 8;
  }
  int bBase[4];
#pragma unroll
  for (int r = 0; r < 4; ++r) bBase[r] = (wave * 4 + r) * 512 + lane * 8;

  f32x4 acc[2][4];
#pragma unroll
  for (int i = 0; i < 2; ++i)
#pragma unroll
    for (int r = 0; r < 4; ++r) acc[i][r] = (f32x4){0.f, 0.f, 0.f, 0.f};

  auto loadA = [&](int kc, uint4 (&dst)[2][2]) {
#pragma unroll
    for (int i = 0; i < 2; ++i) {
      if (AF32) {
        const float* ap = (const float*)Av + aOff[i] + kc * 32;
        float4 f0 = *(const float4*)ap;
        float4 f1 = *(const float4*)(ap + 4);
        dst[i][0] = make_uint4(f2bfx2(f0.x), f2bfx2(f0.y), f2bfx2(f0.z), f2bfx2(f0.w));
        dst[i][1] = make_uint4(f2bfx2(f1.x), f2bfx2(f1.y), f2bfx2(f1.z), f2bfx2(f1.w));
      } else {
        const u32* ap = (const u32*)Av + aOff[i] + kc * 32;
        dst[i][0] = *(const uint4*)ap;
        dst[i][1] = *(const uint4*)(ap + 4);
      }
    }
  };
  auto loadB = [&](int kc, uint4 (&bh)[4], uint4 (&bl)[4]) {
#pragma unroll
    for (int r = 0; r < 4; ++r) {
      bh[r] = *(const uint4*)(WhiT + bBase[r] + kc * 8192);
      bl[r] = *(const uint4*)(WloT + bBase[r] + kc * 8192);
    }
  };

  uint4 curA[2][2], nxtA[2][2], cBH[4], cBL[4], nBH[4], nBL[4];
  loadA(0, curA);
  loadB(0, cBH, cBL);

#pragma unroll
  for (int kc = 0; kc < NK; ++kc) {
    if (kc + 1 < NK) {
      loadA(kc + 1, nxtA);
      loadB(kc + 1, nBH, nBL);
    }
    bf16x8 ah[2], al[2];
    unpack8(curA[0][0], curA[0][1], ah[0], al[0]);
    unpack8(curA[1][0], curA[1][1], ah[1], al[1]);
#pragma unroll
    for (int r = 0; r < 4; ++r) {
      bf16x8 bh = as_bf16x8(cBH[r]);
      bf16x8 bl = as_bf16x8(cBL[r]);
#pragma unroll
      for (int i = 0; i < 2; ++i) {
        acc[i][r] = __builtin_amdgcn_mfma_f32_16x16x32_bf16(ah[i], bh, acc[i][r], 0, 0, 0);
        acc[i][r] = __builtin_amdgcn_mfma_f32_16x16x32_bf16(al[i], bh, acc[i][r], 0, 0, 0);
        acc[i][r] = __builtin_amdgcn_mfma_f32_16x16x32_bf16(ah[i], bl, acc[i][r], 0, 0, 0);
      }
    }
    if (kc + 1 < NK) {
#pragma unroll
      for (int i = 0; i < 2; ++i) {
        curA[i][0] = nxtA[i][0];
        curA[i][1] = nxtA[i][1];
      }
#pragma unroll
      for (int r = 0; r < 4; ++r) {
        cBH[r] = nBH[r];
        cBL[r] = nBL[r];
      }
    }
  }

  // epilogue: C/D layout col=lane&15, row=(lane>>4)*4+reg
#pragma unroll
  for (int r = 0; r < 4; ++r) {
    int col = wave * 64 + r * 16 + r16;
    float bv = bias ? bias[col] : 0.f;
#pragma unroll
    for (int i = 0; i < 2; ++i) {
#pragma unroll
      for (int g = 0; g < 4; ++g) {
        int row = row0 + i * 16 + q * 4 + g;
        if (row < nrows) {
          float v = acc[i][r][g] + bv;
          if (RELU) v = fmaxf(v, 0.f);
          C[(size_t)row * 256 + col] = f2bfx2(v);
        }
      }
    }
  }
}

// fused: T = act1(A @ W1 + bias1) kept in 32KB swizzled LDS, C(fp16) = T @ W2.
template <int K1, bool RELU1, bool AF32>
__global__ __launch_bounds__(256, 3) void fused_gemm_kernel(
    const void* __restrict__ Av, const u16* __restrict__ W1h, const u16* __restrict__ W1l,
    const float* __restrict__ bias1, const u16* __restrict__ W2h, const u16* __restrict__ W2l,
    u16* __restrict__ C, int nrows) {
  constexpr int NK1 = K1 / 32;
  __shared__ u32 T[32 * 256];  // 32KB swizzled bfx2 tile
  const int tid = threadIdx.x;
  const int lane = tid & 63;
  const int wave = tid >> 6;
  const int row0 = blockIdx.x * 32;
  const int q = lane >> 4;
  const int r16 = lane & 15;

  int bBase[4];
#pragma unroll
  for (int r = 0; r < 4; ++r) bBase[r] = (wave * 4 + r) * 512 + lane * 8;

  f32x4 acc[2][4];
#pragma unroll
  for (int i = 0; i < 2; ++i)
#pragma unroll
    for (int r = 0; r < 4; ++r) acc[i][r] = (f32x4){0.f, 0.f, 0.f, 0.f};

  // ---------- phase 1: A @ W1 ----------
  {
    int aOff[2];
#pragma unroll
    for (int i = 0; i < 2; ++i) {
      int row = row0 + i * 16 + r16;
      if (row > nrows - 1) row = nrows - 1;
      aOff[i] = row * K1 + q * 8;
    }
    auto loadA = [&](int kc, uint4 (&dst)[2][2]) {
#pragma unroll
      for (int i = 0; i < 2; ++i) {
        if (AF32) {
          const float* ap = (const float*)Av + aOff[i] + kc * 32;
          float4 f0 = *(const float4*)ap;
          float4 f1 = *(const float4*)(ap + 4);
          dst[i][0] = make_uint4(f2bfx2(f0.x), f2bfx2(f0.y), f2bfx2(f0.z), f2bfx2(f0.w));
          dst[i][1] = make_uint4(f2bfx2(f1.x), f2bfx2(f1.y), f2bfx2(f1.z), f2bfx2(f1.w));
        } else {
          const u32* ap = (const u32*)Av + aOff[i] + kc * 32;
          dst[i][0] = *(const uint4*)ap;
          dst[i][1] = *(const uint4*)(ap + 4);
        }
      }
    };
    auto loadB1 = [&](int kc, uint4 (&bh)[4], uint4 (&bl)[4]) {
#pragma unroll
      for (int r = 0; r < 4; ++r) {
        bh[r] = *(const uint4*)(W1h + bBase[r] + kc * 8192);
        bl[r] = *(const uint4*)(W1l + bBase[r] + kc * 8192);
      }
    };

    uint4 curA[2][2], nxtA[2][2], cBH[4], cBL[4], nBH[4], nBL[4];
    loadA(0, curA);
    loadB1(0, cBH, cBL);
#pragma unroll
    for (int kc = 0; kc < NK1; ++kc) {
      if (kc + 1 < NK1) {
        loadA(kc + 1, nxtA);
        loadB1(kc + 1, nBH, nBL);
      }
      bf16x8 ah[2], al[2];
      unpack8(curA[0][0], curA[0][1], ah[0], al[0]);
      unpack8(curA[1][0], curA[1][1], ah[1], al[1]);
#pragma unroll
      for (int r = 0; r < 4; ++r) {
        bf16x8 bh = as_bf16x8(cBH[r]);
        bf16x8 bl = as_bf16x8(cBL[r]);
#pragma unroll
        for (int i = 0; i < 2; ++i) {
          acc[i][r] = __builtin_amdgcn_mfma_f32_16x16x32_bf16(ah[i], bh, acc[i][r], 0, 0, 0);
          acc[i][r] = __builtin_amdgcn_mfma_f32_16x16x32_bf16(al[i], bh, acc[i][r], 0, 0, 0);
          acc[i][r] = __builtin_amdgcn_mfma_f32_16x16x32_bf16(ah[i], bl, acc[i][r], 0, 0, 0);
        }
      }
      if (kc + 1 < NK1) {
#pragma unroll
        for (int i = 0; i < 2; ++i) {
          curA[i][0] = nxtA[i][0];
          curA[i][1] = nxtA[i][1];
        }
#pragma unroll
        for (int r = 0; r < 4; ++r) {
          cBH[r] = nBH[r];
          cBL[r] = nBL[r];
        }
      }
    }
  }

  // epilogue 1 -> swizzled LDS tile (local rows 0..31)
#pragma unroll
  for (int r = 0; r < 4; ++r) {
    int col = wave * 64 + r * 16 + r16;
    float bv = bias1[col];
#pragma unroll
    for (int i = 0; i < 2; ++i) {
#pragma unroll
      for (int g = 0; g < 4; ++g) {
        int row = i * 16 + q * 4 + g;
        float v = acc[i][r][g] + bv;
        if (RELU1) v = fmaxf(v, 0.f);
        *(u32*)((char*)T + SWZ(row, (row * 256 + col) * 4)) = f2bfx2(v);
      }
    }
  }

  // ---------- phase 2: T @ W2 ----------
#pragma unroll
  for (int i = 0; i < 2; ++i)
#pragma unroll
    for (int r = 0; r < 4; ++r) acc[i][r] = (f32x4){0.f, 0.f, 0.f, 0.f};

  auto loadB2 = [&](int kc, uint4 (&bh)[4], uint4 (&bl)[4]) {
#pragma unroll
    for (int r = 0; r < 4; ++r) {
      bh[r] = *(const uint4*)(W2h + bBase[r] + kc * 8192);
      bl[r] = *(const uint4*)(W2l + bBase[r] + kc * 8192);
    }
  };

  uint4 cBH[4], cBL[4], nBH[4], nBL[4];
  loadB2(0, cBH, cBL);  // issued before barrier; doesn't touch LDS
  __syncthreads();

#pragma unroll
  for (int kc = 0; kc < 8; ++kc) {
    if (kc + 1 < 8) loadB2(kc + 1, nBH, nBL);
    bf16x8 ah[2], al[2];
#pragma unroll
    for (int i = 0; i < 2; ++i) {
      int row = i * 16 + r16;
      int base = row * 1024 + kc * 128 + q * 32;
      uint4 a0 = *(const uint4*)((char*)T + SWZ(row, base));
      uint4 a1 = *(const uint4*)((char*)T + SWZ(row, base + 16));
      unpack8(a0, a1, ah[i], al[i]);
    }
#pragma unroll
    for (int r = 0; r < 4; ++r) {
      bf16x8 bh = as_bf16x8(cBH[r]);
      bf16x8 bl = as_bf16x8(cBL[r]);
#pragma unroll
      for (int i = 0; i < 2; ++i) {
        acc[i][r] = __builtin_amdgcn_mfma_f32_16x16x32_bf16(ah[i], bh, acc[i][r], 0, 0, 0);
        acc[i][r] = __builtin_amdgcn_mfma_f32_16x16x32_bf16(al[i], bh, acc[i][r], 0, 0, 0);
        acc[i][r] = __builtin_amdgcn_mfma_f32_16x16x32_bf16(ah[i], bl, acc[i][r], 0, 0, 0);
      }
    }
    if (kc + 1 < 8) {
#pragma unroll
      for (int r = 0; r < 4; ++r) {
        cBH[r] = nBH[r];
        cBL[r] = nBL[r];
      }
    }
  }

  // epilogue 2: write m as fp16 (conv bias applied in gather)
#pragma unroll
  for (int r = 0; r < 4; ++r) {
    int col = wave * 64 + r * 16 + r16;
#pragma unroll
    for (int i = 0; i < 2; ++i) {
#pragma unroll
      for (int g = 0; g < 4; ++g) {
        int row = row0 + i * 16 + q * 4 + g;
        if (row < nrows) C[(size_t)row * 256 + col] = f2h(acc[i][r][g]);
      }
    }
  }
}

// ---------------- GCN gather: m fp16 in, h_agg bfx2 out ----------------

__global__ __launch_bounds__(256) void gather_kernel(
    const u16* __restrict__ m, const int* __restrict__ off,
    const int* __restrict__ csr_src, const float* __restrict__ dis,
    const float* __restrict__ bias, u32* __restrict__ out, int n) {
  int node = blockIdx.x * 4 + (threadIdx.x >> 6);
  if (node >= n) return;
  int lane = threadIdx.x & 63;
  float di = dis[node];
  uint2 v = *(const uint2*)(m + (size_t)node * DD + lane * 4);
  float w = di * di;
  float ax = w * h2f((u16)(v.x & 0xffff)), ay = w * h2f((u16)(v.x >> 16));
  float az = w * h2f((u16)(v.y & 0xffff)), aw = w * h2f((u16)(v.y >> 16));
  int e0 = off[node], e1 = off[node + 1];
  int e = e0;
  for (; e + 3 < e1; e += 4) {
    int s0 = csr_src[e], s1 = csr_src[e + 1], s2 = csr_src[e + 2], s3 = csr_src[e + 3];
    float w0 = dis[s0] * di, w1 = dis[s1] * di, w2 = dis[s2] * di, w3 = dis[s3] * di;
    uint2 u0 = *(const uint2*)(m + (size_t)s0 * DD + lane * 4);
    uint2 u1 = *(const uint2*)(m + (size_t)s1 * DD + lane * 4);
    uint2 u2 = *(const uint2*)(m + (size_t)s2 * DD + lane * 4);
    uint2 u3 = *(const uint2*)(m + (size_t)s3 * DD + lane * 4);
    ax = fmaf(w0, h2f((u16)(u0.x & 0xffff)), ax); ay = fmaf(w0, h2f((u16)(u0.x >> 16)), ay);
    az = fmaf(w0, h2f((u16)(u0.y & 0xffff)), az); aw = fmaf(w0, h2f((u16)(u0.y >> 16)), aw);
    ax = fmaf(w1, h2f((u16)(u1.x & 0xffff)), ax); ay = fmaf(w1, h2f((u16)(u1.x >> 16)), ay);
    az = fmaf(w1, h2f((u16)(u1.y & 0xffff)), az); aw = fmaf(w1, h2f((u16)(u1.y >> 16)), aw);
    ax = fmaf(w2, h2f((u16)(u2.x & 0xffff)), ax); ay = fmaf(w2, h2f((u16)(u2.x >> 16)), ay);
    az = fmaf(w2, h2f((u16)(u2.y & 0xffff)), az); aw = fmaf(w2, h2f((u16)(u2.y >> 16)), aw);
    ax = fmaf(w3, h2f((u16)(u3.x & 0xffff)), ax); ay = fmaf(w3, h2f((u16)(u3.x >> 16)), ay);
    az = fmaf(w3, h2f((u16)(u3.y & 0xffff)), az); aw = fmaf(w3, h2f((u16)(u3.y >> 16)), aw);
  }
  for (; e < e1; ++e) {
    int s0 = csr_src[e];
    float w0 = dis[s0] * di;
    uint2 u0 = *(const uint2*)(m + (size_t)s0 * DD + lane * 4);
    ax = fmaf(w0, h2f((u16)(u0.x & 0xffff)), ax); ay = fmaf(w0, h2f((u16)(u0.x >> 16)), ay);
    az = fmaf(w0, h2f((u16)(u0.y & 0xffff)), az); aw = fmaf(w0, h2f((u16)(u0.y >> 16)), aw);
  }
  float4 bb = *(const float4*)(bias + lane * 4);
  uint4 oo;
  oo.x = f2bfx2(fmaxf(ax + bb.x, 0.f));
  oo.y = f2bfx2(fmaxf(ay + bb.y, 0.f));
  oo.z = f2bfx2(fmaxf(az + bb.z, 0.f));
  oo.w = f2bfx2(fmaxf(aw + bb.w, 0.f));
  *(uint4*)(out + (size_t)node * DD + lane * 4) = oo;
}

// ---------------- BatchNorm stats ----------------

__global__ void bn_partial_kernel(const u32* __restrict__ h, float* __restrict__ sums, int n) {
  int c = threadIdx.x;
  float s = 0.f, q = 0.f;
  for (int r = blockIdx.x; r < n; r += gridDim.x) {
    float v = bfx2_to_f(h[(size_t)r * DD + c]);
    s += v;
    q += v * v;
  }
  atomicAdd(&sums[c], s);
  atomicAdd(&sums[DD + c], q);
}

__global__ void bn_finalize_kernel(const float* __restrict__ sums, const float* __restrict__ g,
                                   const float* __restrict__ b, float* __restrict__ scale,
                                   float* __restrict__ shift, float inv_n) {
  int c = threadIdx.x;
  float mu = sums[c] * inv_n;
  float var = sums[DD + c] * inv_n - mu * mu;
  float inv = rsqrtf(var + 1e-5f);
  float sc = g[c] * inv;
  scale[c] = sc;
  shift[c] = b[c] - mu * sc;
}

// ---------------- global mean pool ----------------

__global__ void pool_kernel(const u32* __restrict__ h, const int* __restrict__ batch,
                            float* __restrict__ pooled, int n) {
  int g = blockIdx.x;
  int c = threadIdx.x;
  int lo = 0, hi = n;
  while (lo < hi) { int mid = (lo + hi) >> 1; if (batch[mid] < g) lo = mid + 1; else hi = mid; }
  int start = lo;
  hi = n;
  while (lo < hi) { int mid = (lo + hi) >> 1; if (batch[mid] <= g) lo = mid + 1; else hi = mid; }
  int end = lo;
  float a0 = 0.f, a1 = 0.f, a2 = 0.f, a3 = 0.f;
  int r = start;
  for (; r + 3 < end; r += 4) {
    a0 += bfx2_to_f(h[(size_t)(r + 0) * DD + c]);
    a1 += bfx2_to_f(h[(size_t)(r + 1) * DD + c]);
    a2 += bfx2_to_f(h[(size_t)(r + 2) * DD + c]);
    a3 += bfx2_to_f(h[(size_t)(r + 3) * DD + c]);
  }
  for (; r < end; ++r) a0 += bfx2_to_f(h[(size_t)r * DD + c]);
  float s = (a0 + a1) + (a2 + a3);
  int cg = end - start;
  pooled[g * DD + c] = s / (float)(cg > 1 ? cg : 1);
}

// ---------------- MLP head ----------------

__global__ void mlp1_kernel(const float* __restrict__ pooled, const float* __restrict__ W,
                            const float* __restrict__ b, float* __restrict__ out) {
  __shared__ float p[256];
  int g = blockIdx.x;
  int j = blockIdx.y * 256 + threadIdx.x;
  p[threadIdx.x] = pooled[g * 256 + threadIdx.x];
  __syncthreads();
  float acc = b[j];
#pragma unroll 8
  for (int k = 0; k < 512; ++k) acc = fmaf(p[k & 255], W[k * 512 + j], acc);
  out[g * 512 + j] = fmaxf(acc, 0.f);
}

__global__ void mlp2_kernel(const float* __restrict__ z1, const float* __restrict__ W,
                            const float* __restrict__ b, float* __restrict__ out) {
  __shared__ float p[512];
  int g = blockIdx.x;
  p[threadIdx.x] = z1[g * 512 + threadIdx.x];
  p[256 + threadIdx.x] = z1[g * 512 + 256 + threadIdx.x];
  __syncthreads();
  float acc = b[threadIdx.x];
#pragma unroll 8
  for (int k = 0; k < 512; ++k) acc = fmaf(p[k], W[k * 256 + threadIdx.x], acc);
  out[g * 256 + threadIdx.x] = fmaxf(acc, 0.f);
}

__global__ void mlp3_kernel(const float* __restrict__ z2, const float* __restrict__ W,
                            const float* __restrict__ b, float* __restrict__ out) {
  int g = blockIdx.x;
  int lane = threadIdx.x;
  float acc[10];
#pragma unroll
  for (int o = 0; o < 10; ++o) acc[o] = 0.f;
  for (int k = lane; k < 256; k += 64) {
    float v = z2[g * 256 + k];
#pragma unroll
    for (int o = 0; o < 10; ++o) acc[o] = fmaf(v, W[k * 10 + o], acc[o]);
  }
#pragma unroll
  for (int o = 0; o < 10; ++o) {
    float s = acc[o];
    for (int d = 32; d > 0; d >>= 1) s += __shfl_down(s, d);
    if (lane == 0) out[g * 10 + o] = s + b[o];
  }
}

// ---------------- launch ----------------

extern "C" void kernel_launch(void* const* d_in, const int* in_sizes, int n_in,
                              void* d_out, int out_size, void* d_ws, size_t ws_size,
                              hipStream_t stream) {
  const float* x = (const float*)d_in[0];
  const int* ei = (const int*)d_in[1];
  const int* batch = (const int*)d_in[2];
  const float* fl_W = (const float*)d_in[3];
  const float* fl_b = (const float*)d_in[4];
  const float* conv1_W = (const float*)d_in[5];
  const float* conv1_b = (const float*)d_in[6];
  const float* tr1_W = (const float*)d_in[7];
  const float* tr1_b = (const float*)d_in[8];
  const float* bn1_g = (const float*)d_in[9];
  const float* bn1_b = (const float*)d_in[10];
  const float* convs_W = (const float*)d_in[11];
  const float* convs_b = (const float*)d_in[12];
  const float* trs_W = (const float*)d_in[13];
  const float* trs_b = (const float*)d_in[14];
  const float* bns_g = (const float*)d_in[15];
  const float* bns_b = (const float*)d_in[16];
  const float* l1_W = (const float*)d_in[17];
  const float* l1_b = (const float*)d_in[18];
  const float* l2_W = (const float*)d_in[19];
  const float* l2_b = (const float*)d_in[20];
  const float* l3_W = (const float*)d_in[21];
  const float* l3_b = (const float*)d_in[22];

  const int N = in_sizes[0] / 128;
  const int E = in_sizes[1] / 2;
  const int G = out_size / 10;
  const int NL = in_sizes[11] / (256 * 256);
  const int* src = ei;
  const int* dst = ei + E;

  char* ws = (char*)d_ws;
  size_t o = 0;
  auto alloc = [&](size_t bytes) -> char* {
    o = (o + 255) & ~(size_t)255;
    char* p = ws + o;
    o += bytes;
    return p;
  };
  u32* hA = (u32*)alloc((size_t)N * DD * 4);   // h_agg (gather out, bfx2)
  u32* hB = (u32*)alloc((size_t)N * DD * 4);   // final h (bfx2)
  u16* mF = (u16*)alloc((size_t)N * DD * 2);   // m (conv out, fp16)
  float* dis = (float*)alloc((size_t)N * 4);
  int* cnt = (int*)alloc((size_t)N * 4);
  int* off = (int*)alloc((size_t)(N + 1) * 4);
  int* cursor = (int*)alloc((size_t)N * 4);
  int* bsum = (int*)alloc(64 * 4);
  int* csr = (int*)alloc((size_t)E * 4);
  float* bnsums = (float*)alloc((size_t)(1 + NL) * 512 * 4);
  float* scalev = (float*)alloc(256 * 4);
  float* shiftv = (float*)alloc(256 * 4);
  float* pooled = (float*)alloc((size_t)G * 256 * 4);
  float* z1 = (float*)alloc((size_t)G * 512 * 4);
  float* z2 = (float*)alloc((size_t)G * 256 * 4);
  u16* flHi = (u16*)alloc(128 * 256 * 2);
  u16* flLo = (u16*)alloc(128 * 256 * 2);
  u16* cvHi = (u16*)alloc((size_t)(1 + NL) * 256 * 256 * 2);
  u16* cvLo = (u16*)alloc((size_t)(1 + NL) * 256 * 256 * 2);
  u16* trHi = (u16*)alloc(256 * 256 * 2);
  u16* trLo = (u16*)alloc(256 * 256 * 2);
  float* trBias = (float*)alloc(256 * 4);

  dim3 b256(256);
  const int nblk = (N + 31) / 32;  // 32-row blocks

  // CSR build
  zero_i32_kernel<<<(N + 255) / 256, b256, 0, stream>>>(cnt, N);
  count_kernel<<<(E + 255) / 256, b256, 0, stream>>>(dst, cnt, E);
  int nb = (N + 1023) / 1024;
  scan_block_kernel<<<nb, b256, 0, stream>>>(cnt, off, bsum, N);
  scan_partials_kernel<<<1, 64, 0, stream>>>(bsum, nb);
  finalize_kernel<<<(N + 255) / 256, b256, 0, stream>>>(off, bsum, cursor, cnt, dis, N, E);
  fill_kernel<<<(E + 255) / 256, b256, 0, stream>>>(src, dst, cursor, csr, E);

  // static weight splits (packed) + zero all BN slots once
  dim3 wgrid(256, 2 + NL);
  wsplit_all_kernel<<<wgrid, b256, 0, stream>>>(fl_W, conv1_W, convs_W, flHi, flLo, cvHi, cvLo);
  zero_f32_kernel<<<(int)(((1 + NL) * 512 + 255) / 256), b256, 0, stream>>>(bnsums, (1 + NL) * 512);

  // fused fl + conv1 -> m1 (fp16)
  fused_gemm_kernel<128, false, true><<<nblk, b256, 0, stream>>>(x, flHi, flLo, fl_b, cvHi, cvLo,
                                                                 mF, N);

  for (int L = 0; L < 1 + NL; ++L) {
    const float* bc = (L == 0) ? conv1_b : convs_b + (size_t)(L - 1) * 256;
    const float* gg = (L == 0) ? bn1_g : bns_g + (size_t)(L - 1) * 256;
    const float* gb = (L == 0) ? bn1_b : bns_b + (size_t)(L - 1) * 256;
    const float* Wt = (L == 0) ? tr1_W : trs_W + (size_t)(L - 1) * 256 * 256;
    const float* bt = (L == 0) ? tr1_b : trs_b + (size_t)(L - 1) * 256;
    float* slot = bnsums + (size_t)L * 512;

    gather_kernel<<<(N + 3) / 4, b256, 0, stream>>>(mF, off, csr, dis, bc, hA, N);
    bn_partial_kernel<<<1024, b256, 0, stream>>>(hA, slot, N);
    bn_finalize_kernel<<<1, b256, 0, stream>>>(slot, gg, gb, scalev, shiftv, 1.0f / (float)N);
    wsplit_fold_kernel<<<256, b256, 0, stream>>>(Wt, scalev, shiftv, bt, trHi, trLo, trBias);
    if (L < NL) {
      // fused tr(L) + conv(L+1) -> m_{L+1} (fp16)
      fused_gemm_kernel<256, true, false><<<nblk, b256, 0, stream>>>(
          hA, trHi, trLo, trBias, cvHi + (size_t)(L + 1) * 65536, cvLo + (size_t)(L + 1) * 65536,
          mF, N);
    } else {
      // final tr -> h (bfx2)
      gemm_mfma_kernel<256, true, false><<<nblk, b256, 0, stream>>>(hA, trHi, trLo, trBias, hB, N);
    }
  }

  pool_kernel<<<G, b256, 0, stream>>>(hB, batch, pooled, N);
  dim3 m1grid(G, 2);
  mlp1_kernel<<<m1grid, b256, 0, stream>>>(pooled, l1_W, l1_b, z1);
  mlp2_kernel<<<G, b256, 0, stream>>>(z1, l2_W, l2_b, z2);
  mlp3_kernel<<<G, 64, 0, stream>>>(z2, l3_W, l3_b, (float*)d_out);
}

// Round 8
// 1025.406 us; speedup vs baseline: 1.9291x; 1.0299x over previous
//
#include <hip/hip_runtime.h>

#define DD 256

typedef unsigned short u16;
typedef unsigned int u32;
using bf16x8 = __attribute__((ext_vector_type(8))) short;  // 8 bf16 (4 VGPRs)
using f32x4  = __attribute__((ext_vector_type(4))) float;

#define GLB_PTR(p) ((const __attribute__((address_space(1))) u32*)(p))
#define LDS_PTR(p) ((__attribute__((address_space(3))) u32*)(p))

// ---- bfx2 helpers: uint32 = hi_bf16 (bits 15:0) | lo_bf16 (bits 31:16) ----

__device__ __forceinline__ u32 f2bfx2(float v) {
  u32 b = __float_as_uint(v);
  u32 hi = (b + 0x7fffu + ((b >> 16) & 1u)) >> 16;  // RNE bf16
  float hf = __uint_as_float(hi << 16);
  float lof = v - hf;
  u32 b2 = __float_as_uint(lof);
  u32 lo = (b2 + 0x7fffu + ((b2 >> 16) & 1u)) >> 16;
  return hi | (lo << 16);
}

__device__ __forceinline__ float bfx2_to_f(u32 e) {
  return __uint_as_float(e << 16) + __uint_as_float(e & 0xffff0000u);
}

// ---- fp16 helpers ----
__device__ __forceinline__ u16 f2h(float f) {
  _Float16 h = (_Float16)f;
  return __builtin_bit_cast(unsigned short, h);
}
__device__ __forceinline__ float h2f(u16 x) {
  return (float)__builtin_bit_cast(_Float16, x);
}

__device__ __forceinline__ bf16x8 as_bf16x8(uint4 u) {
  union { uint4 u; bf16x8 v; } c;
  c.u = u;
  return c.v;
}

// deinterleave 8 packed bfx2 (a,b) into hi-plane / lo-plane bf16x8
__device__ __forceinline__ void unpack8(uint4 a, uint4 b, bf16x8& hi, bf16x8& lo) {
  union { u32 w[4]; bf16x8 v; } H, L;
  H.w[0] = __builtin_amdgcn_perm(a.y, a.x, 0x05040100u);
  L.w[0] = __builtin_amdgcn_perm(a.y, a.x, 0x07060302u);
  H.w[1] = __builtin_amdgcn_perm(a.w, a.z, 0x05040100u);
  L.w[1] = __builtin_amdgcn_perm(a.w, a.z, 0x07060302u);
  H.w[2] = __builtin_amdgcn_perm(b.y, b.x, 0x05040100u);
  L.w[2] = __builtin_amdgcn_perm(b.y, b.x, 0x07060302u);
  H.w[3] = __builtin_amdgcn_perm(b.w, b.z, 0x05040100u);
  L.w[3] = __builtin_amdgcn_perm(b.w, b.z, 0x07060302u);
  hi = H.v;
  lo = L.v;
}

// packed B-plane layout: fragment-contiguous. off = ((kc*4+w)*4+r)*512 + lane*8
__device__ __forceinline__ int packoff(int col, int k) {
  int w = col >> 6, r = (col >> 4) & 3, c16 = col & 15;
  int kc = k >> 5, q = (k >> 3) & 3, j = k & 7;
  return ((kc * 4 + w) * 4 + r) * 512 + (q * 16 + c16) * 8 + j;
}

// ---------------- CSR build ----------------

__global__ void zero_i32_kernel(int* p, int n) {
  int i = blockIdx.x * 256 + threadIdx.x;
  if (i < n) p[i] = 0;
}

__global__ void zero_f32_kernel(float* p, int n) {
  int i = blockIdx.x * 256 + threadIdx.x;
  if (i < n) p[i] = 0.f;
}

__global__ void count_kernel(const int* __restrict__ dst, int* __restrict__ cnt, int e) {
  int i = blockIdx.x * 256 + threadIdx.x;
  if (i < e) atomicAdd(&cnt[dst[i]], 1);
}

__global__ void scan_block_kernel(const int* __restrict__ cnt, int* __restrict__ out,
                                  int* __restrict__ bsum, int n) {
  __shared__ int sh[256];
  int tid = threadIdx.x;
  int base = blockIdx.x * 1024 + tid * 4;
  int v0 = (base + 0 < n) ? cnt[base + 0] : 0;
  int v1 = (base + 1 < n) ? cnt[base + 1] : 0;
  int v2 = (base + 2 < n) ? cnt[base + 2] : 0;
  int v3 = (base + 3 < n) ? cnt[base + 3] : 0;
  int s = v0 + v1 + v2 + v3;
  sh[tid] = s;
  __syncthreads();
  for (int d = 1; d < 256; d <<= 1) {
    int t = (tid >= d) ? sh[tid - d] : 0;
    __syncthreads();
    sh[tid] += t;
    __syncthreads();
  }
  int excl = sh[tid] - s;
  if (base + 0 < n) out[base + 0] = excl;
  excl += v0;
  if (base + 1 < n) out[base + 1] = excl;
  excl += v1;
  if (base + 2 < n) out[base + 2] = excl;
  excl += v2;
  if (base + 3 < n) out[base + 3] = excl;
  if (tid == 255) bsum[blockIdx.x] = sh[255];
}

__global__ void scan_partials_kernel(int* bsum, int nb) {
  if (threadIdx.x == 0 && blockIdx.x == 0) {
    int acc = 0;
    for (int i = 0; i < nb; ++i) { int t = bsum[i]; bsum[i] = acc; acc += t; }
  }
}

__global__ void finalize_kernel(int* __restrict__ off, const int* __restrict__ bsum,
                                int* __restrict__ cursor, const int* __restrict__ cnt,
                                float* __restrict__ dis, int n, int e) {
  int i = blockIdx.x * 256 + threadIdx.x;
  if (i < n) {
    int o = off[i] + bsum[i >> 10];
    off[i] = o;
    cursor[i] = o;
    dis[i] = rsqrtf((float)(cnt[i] + 1));  // deg includes self-loop
  }
  if (i == 0 && blockIdx.x == 0) off[n] = e;
}

__global__ void fill_kernel(const int* __restrict__ src, const int* __restrict__ dst,
                            int* __restrict__ cursor, int* __restrict__ csr_src, int e) {
  int i = blockIdx.x * 256 + threadIdx.x;
  if (i < e) {
    int d = dst[i];
    int p = atomicAdd(&cursor[d], 1);
    csr_src[p] = src[i];
  }
}

// ---------------- activation prep: x fp32 -> bfx2 ----------------

__global__ void xsplit_kernel(const float* __restrict__ x, u32* __restrict__ xq, int n) {
  int i = blockIdx.x * 256 + threadIdx.x;
  if (i < n) xq[i] = f2bfx2(x[i]);
}

// ---------------- weight prep (packed layout) ----------------

__global__ void wsplit_all_kernel(const float* __restrict__ fl_W, const float* __restrict__ conv1_W,
                                  const float* __restrict__ convs_W, u16* __restrict__ flHi,
                                  u16* __restrict__ flLo, u16* __restrict__ cvHi,
                                  u16* __restrict__ cvLo) {
  int j = blockIdx.x;   // output column
  int m = blockIdx.y;   // matrix id
  int k = threadIdx.x;  // input row
  if (m == 0) {
    if (k < 128) {
      u32 p = f2bfx2(fl_W[(size_t)k * 256 + j]);
      int off = packoff(j, k);
      flHi[off] = (u16)(p & 0xffffu);
      flLo[off] = (u16)(p >> 16);
    }
  } else {
    int c = m - 1;
    const float* W = (c == 0) ? conv1_W : convs_W + (size_t)(c - 1) * 65536;
    u32 p = f2bfx2(W[(size_t)k * 256 + j]);
    size_t off = (size_t)c * 65536 + packoff(j, k);
    cvHi[off] = (u16)(p & 0xffffu);
    cvLo[off] = (u16)(p >> 16);
  }
}

// tr prep: W' = diag(scale)@Wt packed; bias_out = bt + shift@Wt. grid 256.
__global__ void wsplit_fold_kernel(const float* __restrict__ W, const float* __restrict__ scale,
                                   const float* __restrict__ shift, const float* __restrict__ bt,
                                   u16* __restrict__ WhiT, u16* __restrict__ WloT,
                                   float* __restrict__ bias_out) {
  __shared__ float red[256];
  int j = blockIdx.x;
  int k = threadIdx.x;
  float w = W[(size_t)k * 256 + j];
  u32 p = f2bfx2(w * scale[k]);
  int off = packoff(j, k);
  WhiT[off] = (u16)(p & 0xffffu);
  WloT[off] = (u16)(p >> 16);
  red[k] = shift[k] * w;
  __syncthreads();
  for (int d = 128; d > 0; d >>= 1) {
    if (k < d) red[k] += red[k + d];
    __syncthreads();
  }
  if (k == 0) bias_out[j] = bt[j] + red[0];
}

// ---------------- MFMA GEMM, LDS-staged A (m97 structure) ----------------
// Block = 64 rows x 256 cols, 4 waves; wave owns 64 cols, all 64 rows (acc 4x4).
// A: global_load_lds dwordx4 -> double-buffered 8KB LDS stage, pre-swizzled
// source (q' = q ^ (row&3), 32B granule) so ds_read_b128 avoids 16-way conflicts.
// B: packed fragment-contiguous planes, direct L2 loads.
// Split product ah*bh + al*bh + ah*bl ~ fp32 precision.

#define SWZ(row, byteoff) ((byteoff) ^ (((row) & 7) << 4))

// A-frag read from staged LDS
__device__ __forceinline__ void afrag(const u32* As, int R, int q, bf16x8& ah, bf16x8& al) {
  const u32* ap = As + R * 32 + ((((q * 32) ^ ((R & 3) << 5))) >> 2);
  uint4 a0 = *(const uint4*)ap;
  uint4 a1 = *(const uint4*)(ap + 4);
  unpack8(a0, a1, ah, al);
}

// standalone: C(bfx2) = act(A @ W + bias)
template <int K, bool RELU>
__global__ __launch_bounds__(256) void gemm_mfma_kernel(
    const u32* __restrict__ Aq, const u16* __restrict__ WhiT, const u16* __restrict__ WloT,
    const float* __restrict__ bias, u32* __restrict__ C, int nrows) {
  constexpr int NK = K / 32;
  __shared__ __align__(16) u32 As[2][2048];  // 2 x 8KB stages (64 rows x 32 u32)
  const int tid = threadIdx.x;
  const int lane = tid & 63;
  const int wave = tid >> 6;
  const int row0 = blockIdx.x * 64;
  const int q = lane >> 4;
  const int r16 = lane & 15;

  // staging addresses: chunk c in {0,1}; row = c*32 + wave*8 + lane/8
  int sRow[2], sOffU32[2];
#pragma unroll
  for (int c = 0; c < 2; ++c) {
    int row = c * 32 + wave * 8 + (lane >> 3);
    int grow = row0 + row;
    if (grow > nrows - 1) grow = nrows - 1;
    sRow[c] = grow;
    sOffU32[c] = (((lane & 7) * 16) ^ ((row & 3) << 5)) >> 2;
  }

  int bBase[4];
#pragma unroll
  for (int r = 0; r < 4; ++r) bBase[r] = (wave * 4 + r) * 512 + lane * 8;

  f32x4 acc[4][4];
#pragma unroll
  for (int i = 0; i < 4; ++i)
#pragma unroll
    for (int r = 0; r < 4; ++r) acc[i][r] = (f32x4){0.f, 0.f, 0.f, 0.f};

  auto stage = [&](int buf, int kc) {
#pragma unroll
    for (int c = 0; c < 2; ++c) {
      const u32* gsrc = Aq + (size_t)sRow[c] * K + kc * 32 + sOffU32[c];
      u32* ldst = &As[buf][c * 1024 + wave * 256];  // wave-uniform base
      __builtin_amdgcn_global_load_lds(GLB_PTR(gsrc), LDS_PTR(ldst), 16, 0, 0);
    }
  };

  stage(0, 0);
  __syncthreads();

  int buf = 0;
#pragma unroll
  for (int kc = 0; kc < NK; ++kc) {
    if (kc + 1 < NK) stage(buf ^ 1, kc + 1);
    uint4 BH[4], BL[4];
#pragma unroll
    for (int r = 0; r < 4; ++r) {
      BH[r] = *(const uint4*)(WhiT + bBase[r] + kc * 8192);
      BL[r] = *(const uint4*)(WloT + bBase[r] + kc * 8192);
    }
    bf16x8 ah[4], al[4];
#pragma unroll
    for (int i = 0; i < 4; ++i) afrag(As[buf], i * 16 + r16, q, ah[i], al[i]);
#pragma unroll
    for (int r = 0; r < 4; ++r) {
      bf16x8 bh = as_bf16x8(BH[r]);
      bf16x8 bl = as_bf16x8(BL[r]);
#pragma unroll
      for (int i = 0; i < 4; ++i) {
        acc[i][r] = __builtin_amdgcn_mfma_f32_16x16x32_bf16(ah[i], bh, acc[i][r], 0, 0, 0);
        acc[i][r] = __builtin_amdgcn_mfma_f32_16x16x32_bf16(al[i], bh, acc[i][r], 0, 0, 0);
        acc[i][r] = __builtin_amdgcn_mfma_f32_16x16x32_bf16(ah[i], bl, acc[i][r], 0, 0, 0);
      }
    }
    __syncthreads();
    buf ^= 1;
  }

  // epilogue: C/D layout col=lane&15, row=(lane>>4)*4+reg
#pragma unroll
  for (int r = 0; r < 4; ++r) {
    int col = wave * 64 + r * 16 + r16;
    float bv = bias ? bias[col] : 0.f;
#pragma unroll
    for (int i = 0; i < 4; ++i) {
#pragma unroll
      for (int g = 0; g < 4; ++g) {
        int row = row0 + i * 16 + q * 4 + g;
        if (row < nrows) {
          float v = acc[i][r][g] + bv;
          if (RELU) v = fmaxf(v, 0.f);
          C[(size_t)row * 256 + col] = f2bfx2(v);
        }
      }
    }
  }
}

// fused: T = act1(A @ W1 + bias1) kept in 32KB swizzled LDS, C(fp16) = T @ W2.
template <int K1, bool RELU1>
__global__ __launch_bounds__(256) void fused_gemm_kernel(
    const u32* __restrict__ Aq, const u16* __restrict__ W1h, const u16* __restrict__ W1l,
    const float* __restrict__ bias1, const u16* __restrict__ W2h, const u16* __restrict__ W2l,
    u16* __restrict__ C, int nrows) {
  constexpr int NK1 = K1 / 32;
  __shared__ __align__(16) u32 As[2][2048];  // 16KB A stages
  __shared__ __align__(16) u32 T[64 * 256];  // 64KB swizzled bfx2 intermediate
  const int tid = threadIdx.x;
  const int lane = tid & 63;
  const int wave = tid >> 6;
  const int row0 = blockIdx.x * 64;
  const int q = lane >> 4;
  const int r16 = lane & 15;

  int sRow[2], sOffU32[2];
#pragma unroll
  for (int c = 0; c < 2; ++c) {
    int row = c * 32 + wave * 8 + (lane >> 3);
    int grow = row0 + row;
    if (grow > nrows - 1) grow = nrows - 1;
    sRow[c] = grow;
    sOffU32[c] = (((lane & 7) * 16) ^ ((row & 3) << 5)) >> 2;
  }

  int bBase[4];
#pragma unroll
  for (int r = 0; r < 4; ++r) bBase[r] = (wave * 4 + r) * 512 + lane * 8;

  f32x4 acc[4][4];
#pragma unroll
  for (int i = 0; i < 4; ++i)
#pragma unroll
    for (int r = 0; r < 4; ++r) acc[i][r] = (f32x4){0.f, 0.f, 0.f, 0.f};

  auto stage = [&](int buf, int kc) {
#pragma unroll
    for (int c = 0; c < 2; ++c) {
      const u32* gsrc = Aq + (size_t)sRow[c] * K1 + kc * 32 + sOffU32[c];
      u32* ldst = &As[buf][c * 1024 + wave * 256];
      __builtin_amdgcn_global_load_lds(GLB_PTR(gsrc), LDS_PTR(ldst), 16, 0, 0);
    }
  };

  // ---------- phase 1: A @ W1 ----------
  stage(0, 0);
  __syncthreads();
  int buf = 0;
#pragma unroll
  for (int kc = 0; kc < NK1; ++kc) {
    if (kc + 1 < NK1) stage(buf ^ 1, kc + 1);
    uint4 BH[4], BL[4];
#pragma unroll
    for (int r = 0; r < 4; ++r) {
      BH[r] = *(const uint4*)(W1h + bBase[r] + kc * 8192);
      BL[r] = *(const uint4*)(W1l + bBase[r] + kc * 8192);
    }
    bf16x8 ah[4], al[4];
#pragma unroll
    for (int i = 0; i < 4; ++i) afrag(As[buf], i * 16 + r16, q, ah[i], al[i]);
#pragma unroll
    for (int r = 0; r < 4; ++r) {
      bf16x8 bh = as_bf16x8(BH[r]);
      bf16x8 bl = as_bf16x8(BL[r]);
#pragma unroll
      for (int i = 0; i < 4; ++i) {
        acc[i][r] = __builtin_amdgcn_mfma_f32_16x16x32_bf16(ah[i], bh, acc[i][r], 0, 0, 0);
        acc[i][r] = __builtin_amdgcn_mfma_f32_16x16x32_bf16(al[i], bh, acc[i][r], 0, 0, 0);
        acc[i][r] = __builtin_amdgcn_mfma_f32_16x16x32_bf16(ah[i], bl, acc[i][r], 0, 0, 0);
      }
    }
    __syncthreads();
    buf ^= 1;
  }

  // epilogue 1 -> swizzled LDS tile T (local rows 0..63)
#pragma unroll
  for (int r = 0; r < 4; ++r) {
    int col = wave * 64 + r * 16 + r16;
    float bv = bias1[col];
#pragma unroll
    for (int i = 0; i < 4; ++i) {
#pragma unroll
      for (int g = 0; g < 4; ++g) {
        int row = i * 16 + q * 4 + g;
        float v = acc[i][r][g] + bv;
        if (RELU1) v = fmaxf(v, 0.f);
        *(u32*)((char*)T + SWZ(row, (row * 256 + col) * 4)) = f2bfx2(v);
      }
    }
  }

  // ---------- phase 2: T @ W2 ----------
#pragma unroll
  for (int i = 0; i < 4; ++i)
#pragma unroll
    for (int r = 0; r < 4; ++r) acc[i][r] = (f32x4){0.f, 0.f, 0.f, 0.f};

  __syncthreads();

#pragma unroll
  for (int kc = 0; kc < 8; ++kc) {
    uint4 BH[4], BL[4];
#pragma unroll
    for (int r = 0; r < 4; ++r) {
      BH[r] = *(const uint4*)(W2h + bBase[r] + kc * 8192);
      BL[r] = *(const uint4*)(W2l + bBase[r] + kc * 8192);
    }
    bf16x8 ah[4], al[4];
#pragma unroll
    for (int i = 0; i < 4; ++i) {
      int row = i * 16 + r16;
      int base = row * 1024 + kc * 128 + q * 32;
      uint4 a0 = *(const uint4*)((char*)T + SWZ(row, base));
      uint4 a1 = *(const uint4*)((char*)T + SWZ(row, base + 16));
      unpack8(a0, a1, ah[i], al[i]);
    }
#pragma unroll
    for (int r = 0; r < 4; ++r) {
      bf16x8 bh = as_bf16x8(BH[r]);
      bf16x8 bl = as_bf16x8(BL[r]);
#pragma unroll
      for (int i = 0; i < 4; ++i) {
        acc[i][r] = __builtin_amdgcn_mfma_f32_16x16x32_bf16(ah[i], bh, acc[i][r], 0, 0, 0);
        acc[i][r] = __builtin_amdgcn_mfma_f32_16x16x32_bf16(al[i], bh, acc[i][r], 0, 0, 0);
        acc[i][r] = __builtin_amdgcn_mfma_f32_16x16x32_bf16(ah[i], bl, acc[i][r], 0, 0, 0);
      }
    }
  }

  // epilogue 2: write m as fp16 (conv bias applied in gather)
#pragma unroll
  for (int r = 0; r < 4; ++r) {
    int col = wave * 64 + r * 16 + r16;
#pragma unroll
    for (int i = 0; i < 4; ++i) {
#pragma unroll
      for (int g = 0; g < 4; ++g) {
        int row = row0 + i * 16 + q * 4 + g;
        if (row < nrows) C[(size_t)row * 256 + col] = f2h(acc[i][r][g]);
      }
    }
  }
}

// ---------------- GCN gather: m fp16 in, h_agg bfx2 out ----------------

__global__ __launch_bounds__(256) void gather_kernel(
    const u16* __restrict__ m, const int* __restrict__ off,
    const int* __restrict__ csr_src, const float* __restrict__ dis,
    const float* __restrict__ bias, u32* __restrict__ out, int n) {
  int node = blockIdx.x * 4 + (threadIdx.x >> 6);
  if (node >= n) return;
  int lane = threadIdx.x & 63;
  float di = dis[node];
  uint2 v = *(const uint2*)(m + (size_t)node * DD + lane * 4);
  float w = di * di;
  float ax = w * h2f((u16)(v.x & 0xffff)), ay = w * h2f((u16)(v.x >> 16));
  float az = w * h2f((u16)(v.y & 0xffff)), aw = w * h2f((u16)(v.y >> 16));
  int e0 = off[node], e1 = off[node + 1];
  int e = e0;
  for (; e + 3 < e1; e += 4) {
    int s0 = csr_src[e], s1 = csr_src[e + 1], s2 = csr_src[e + 2], s3 = csr_src[e + 3];
    float w0 = dis[s0] * di, w1 = dis[s1] * di, w2 = dis[s2] * di, w3 = dis[s3] * di;
    uint2 u0 = *(const uint2*)(m + (size_t)s0 * DD + lane * 4);
    uint2 u1 = *(const uint2*)(m + (size_t)s1 * DD + lane * 4);
    uint2 u2 = *(const uint2*)(m + (size_t)s2 * DD + lane * 4);
    uint2 u3 = *(const uint2*)(m + (size_t)s3 * DD + lane * 4);
    ax = fmaf(w0, h2f((u16)(u0.x & 0xffff)), ax); ay = fmaf(w0, h2f((u16)(u0.x >> 16)), ay);
    az = fmaf(w0, h2f((u16)(u0.y & 0xffff)), az); aw = fmaf(w0, h2f((u16)(u0.y >> 16)), aw);
    ax = fmaf(w1, h2f((u16)(u1.x & 0xffff)), ax); ay = fmaf(w1, h2f((u16)(u1.x >> 16)), ay);
    az = fmaf(w1, h2f((u16)(u1.y & 0xffff)), az); aw = fmaf(w1, h2f((u16)(u1.y >> 16)), aw);
    ax = fmaf(w2, h2f((u16)(u2.x & 0xffff)), ax); ay = fmaf(w2, h2f((u16)(u2.x >> 16)), ay);
    az = fmaf(w2, h2f((u16)(u2.y & 0xffff)), az); aw = fmaf(w2, h2f((u16)(u2.y >> 16)), aw);
    ax = fmaf(w3, h2f((u16)(u3.x & 0xffff)), ax); ay = fmaf(w3, h2f((u16)(u3.x >> 16)), ay);
    az = fmaf(w3, h2f((u16)(u3.y & 0xffff)), az); aw = fmaf(w3, h2f((u16)(u3.y >> 16)), aw);
  }
  for (; e < e1; ++e) {
    int s0 = csr_src[e];
    float w0 = dis[s0] * di;
    uint2 u0 = *(const uint2*)(m + (size_t)s0 * DD + lane * 4);
    ax = fmaf(w0, h2f((u16)(u0.x & 0xffff)), ax); ay = fmaf(w0, h2f((u16)(u0.x >> 16)), ay);
    az = fmaf(w0, h2f((u16)(u0.y & 0xffff)), az); aw = fmaf(w0, h2f((u16)(u0.y >> 16)), aw);
  }
  float4 bb = *(const float4*)(bias + lane * 4);
  uint4 oo;
  oo.x = f2bfx2(fmaxf(ax + bb.x, 0.f));
  oo.y = f2bfx2(fmaxf(ay + bb.y, 0.f));
  oo.z = f2bfx2(fmaxf(az + bb.z, 0.f));
  oo.w = f2bfx2(fmaxf(aw + bb.w, 0.f));
  *(uint4*)(out + (size_t)node * DD + lane * 4) = oo;
}

// ---------------- BatchNorm stats ----------------

__global__ void bn_partial_kernel(const u32* __restrict__ h, float* __restrict__ sums, int n) {
  int c = threadIdx.x;
  float s = 0.f, q = 0.f;
  for (int r = blockIdx.x; r < n; r += gridDim.x) {
    float v = bfx2_to_f(h[(size_t)r * DD + c]);
    s += v;
    q += v * v;
  }
  atomicAdd(&sums[c], s);
  atomicAdd(&sums[DD + c], q);
}

__global__ void bn_finalize_kernel(const float* __restrict__ sums, const float* __restrict__ g,
                                   const float* __restrict__ b, float* __restrict__ scale,
                                   float* __restrict__ shift, float inv_n) {
  int c = threadIdx.x;
  float mu = sums[c] * inv_n;
  float var = sums[DD + c] * inv_n - mu * mu;
  float inv = rsqrtf(var + 1e-5f);
  float sc = g[c] * inv;
  scale[c] = sc;
  shift[c] = b[c] - mu * sc;
}

// ---------------- global mean pool ----------------

__global__ void pool_kernel(const u32* __restrict__ h, const int* __restrict__ batch,
                            float* __restrict__ pooled, int n) {
  int g = blockIdx.x;
  int c = threadIdx.x;
  int lo = 0, hi = n;
  while (lo < hi) { int mid = (lo + hi) >> 1; if (batch[mid] < g) lo = mid + 1; else hi = mid; }
  int start = lo;
  hi = n;
  while (lo < hi) { int mid = (lo + hi) >> 1; if (batch[mid] <= g) lo = mid + 1; else hi = mid; }
  int end = lo;
  float a0 = 0.f, a1 = 0.f, a2 = 0.f, a3 = 0.f;
  int r = start;
  for (; r + 3 < end; r += 4) {
    a0 += bfx2_to_f(h[(size_t)(r + 0) * DD + c]);
    a1 += bfx2_to_f(h[(size_t)(r + 1) * DD + c]);
    a2 += bfx2_to_f(h[(size_t)(r + 2) * DD + c]);
    a3 += bfx2_to_f(h[(size_t)(r + 3) * DD + c]);
  }
  for (; r < end; ++r) a0 += bfx2_to_f(h[(size_t)r * DD + c]);
  float s = (a0 + a1) + (a2 + a3);
  int cg = end - start;
  pooled[g * DD + c] = s / (float)(cg > 1 ? cg : 1);
}

// ---------------- MLP head ----------------

__global__ void mlp1_kernel(const float* __restrict__ pooled, const float* __restrict__ W,
                            const float* __restrict__ b, float* __restrict__ out) {
  __shared__ float p[256];
  int g = blockIdx.x;
  int j = blockIdx.y * 256 + threadIdx.x;
  p[threadIdx.x] = pooled[g * 256 + threadIdx.x];
  __syncthreads();
  float acc = b[j];
#pragma unroll 8
  for (int k = 0; k < 512; ++k) acc = fmaf(p[k & 255], W[k * 512 + j], acc);
  out[g * 512 + j] = fmaxf(acc, 0.f);
}

__global__ void mlp2_kernel(const float* __restrict__ z1, const float* __restrict__ W,
                            const float* __restrict__ b, float* __restrict__ out) {
  __shared__ float p[512];
  int g = blockIdx.x;
  p[threadIdx.x] = z1[g * 512 + threadIdx.x];
  p[256 + threadIdx.x] = z1[g * 512 + 256 + threadIdx.x];
  __syncthreads();
  float acc = b[threadIdx.x];
#pragma unroll 8
  for (int k = 0; k < 512; ++k) acc = fmaf(p[k], W[k * 256 + threadIdx.x], acc);
  out[g * 256 + threadIdx.x] = fmaxf(acc, 0.f);
}

__global__ void mlp3_kernel(const float* __restrict__ z2, const float* __restrict__ W,
                            const float* __restrict__ b, float* __restrict__ out) {
  int g = blockIdx.x;
  int lane = threadIdx.x;
  float acc[10];
#pragma unroll
  for (int o = 0; o < 10; ++o) acc[o] = 0.f;
  for (int k = lane; k < 256; k += 64) {
    float v = z2[g * 256 + k];
#pragma unroll
    for (int o = 0; o < 10; ++o) acc[o] = fmaf(v, W[k * 10 + o], acc[o]);
  }
#pragma unroll
  for (int o = 0; o < 10; ++o) {
    float s = acc[o];
    for (int d = 32; d > 0; d >>= 1) s += __shfl_down(s, d);
    if (lane == 0) out[g * 10 + o] = s + b[o];
  }
}

// ---------------- launch ----------------

extern "C" void kernel_launch(void* const* d_in, const int* in_sizes, int n_in,
                              void* d_out, int out_size, void* d_ws, size_t ws_size,
                              hipStream_t stream) {
  const float* x = (const float*)d_in[0];
  const int* ei = (const int*)d_in[1];
  const int* batch = (const int*)d_in[2];
  const float* fl_W = (const float*)d_in[3];
  const float* fl_b = (const float*)d_in[4];
  const float* conv1_W = (const float*)d_in[5];
  const float* conv1_b = (const float*)d_in[6];
  const float* tr1_W = (const float*)d_in[7];
  const float* tr1_b = (const float*)d_in[8];
  const float* bn1_g = (const float*)d_in[9];
  const float* bn1_b = (const float*)d_in[10];
  const float* convs_W = (const float*)d_in[11];
  const float* convs_b = (const float*)d_in[12];
  const float* trs_W = (const float*)d_in[13];
  const float* trs_b = (const float*)d_in[14];
  const float* bns_g = (const float*)d_in[15];
  const float* bns_b = (const float*)d_in[16];
  const float* l1_W = (const float*)d_in[17];
  const float* l1_b = (const float*)d_in[18];
  const float* l2_W = (const float*)d_in[19];
  const float* l2_b = (const float*)d_in[20];
  const float* l3_W = (const float*)d_in[21];
  const float* l3_b = (const float*)d_in[22];

  const int N = in_sizes[0] / 128;
  const int E = in_sizes[1] / 2;
  const int G = out_size / 10;
  const int NL = in_sizes[11] / (256 * 256);
  const int* src = ei;
  const int* dst = ei + E;

  char* ws = (char*)d_ws;
  size_t o = 0;
  auto alloc = [&](size_t bytes) -> char* {
    o = (o + 255) & ~(size_t)255;
    char* p = ws + o;
    o += bytes;
    return p;
  };
  u32* hA = (u32*)alloc((size_t)N * DD * 4);   // h_agg (gather out, bfx2)
  u32* hB = (u32*)alloc((size_t)N * DD * 4);   // final h (bfx2); front half doubles as xq
  u16* mF = (u16*)alloc((size_t)N * DD * 2);   // m (conv out, fp16)
  float* dis = (float*)alloc((size_t)N * 4);
  int* cnt = (int*)alloc((size_t)N * 4);
  int* off = (int*)alloc((size_t)(N + 1) * 4);
  int* cursor = (int*)alloc((size_t)N * 4);
  int* bsum = (int*)alloc(64 * 4);
  int* csr = (int*)alloc((size_t)E * 4);
  float* bnsums = (float*)alloc((size_t)(1 + NL) * 512 * 4);
  float* scalev = (float*)alloc(256 * 4);
  float* shiftv = (float*)alloc(256 * 4);
  float* pooled = (float*)alloc((size_t)G * 256 * 4);
  float* z1 = (float*)alloc((size_t)G * 512 * 4);
  float* z2 = (float*)alloc((size_t)G * 256 * 4);
  u16* flHi = (u16*)alloc(128 * 256 * 2);
  u16* flLo = (u16*)alloc(128 * 256 * 2);
  u16* cvHi = (u16*)alloc((size_t)(1 + NL) * 256 * 256 * 2);
  u16* cvLo = (u16*)alloc((size_t)(1 + NL) * 256 * 256 * 2);
  u16* trHi = (u16*)alloc(256 * 256 * 2);
  u16* trLo = (u16*)alloc(256 * 256 * 2);
  float* trBias = (float*)alloc(256 * 4);

  u32* xq = hB;  // x bfx2 (N*128 u32) — dead before hB is written

  dim3 b256(256);
  const int nblk = (N + 63) / 64;  // 64-row blocks

  // CSR build
  zero_i32_kernel<<<(N + 255) / 256, b256, 0, stream>>>(cnt, N);
  count_kernel<<<(E + 255) / 256, b256, 0, stream>>>(dst, cnt, E);
  int nb = (N + 1023) / 1024;
  scan_block_kernel<<<nb, b256, 0, stream>>>(cnt, off, bsum, N);
  scan_partials_kernel<<<1, 64, 0, stream>>>(bsum, nb);
  finalize_kernel<<<(N + 255) / 256, b256, 0, stream>>>(off, bsum, cursor, cnt, dis, N, E);
  fill_kernel<<<(E + 255) / 256, b256, 0, stream>>>(src, dst, cursor, csr, E);

  // prep: x -> bfx2, weight splits (packed), zero BN slots
  xsplit_kernel<<<(N * 128 + 255) / 256, b256, 0, stream>>>(x, xq, N * 128);
  dim3 wgrid(256, 2 + NL);
  wsplit_all_kernel<<<wgrid, b256, 0, stream>>>(fl_W, conv1_W, convs_W, flHi, flLo, cvHi, cvLo);
  zero_f32_kernel<<<(int)(((1 + NL) * 512 + 255) / 256), b256, 0, stream>>>(bnsums, (1 + NL) * 512);

  // fused fl + conv1 -> m1 (fp16)
  fused_gemm_kernel<128, false><<<nblk, b256, 0, stream>>>(xq, flHi, flLo, fl_b, cvHi, cvLo, mF, N);

  for (int L = 0; L < 1 + NL; ++L) {
    const float* bc = (L == 0) ? conv1_b : convs_b + (size_t)(L - 1) * 256;
    const float* gg = (L == 0) ? bn1_g : bns_g + (size_t)(L - 1) * 256;
    const float* gb = (L == 0) ? bn1_b : bns_b + (size_t)(L - 1) * 256;
    const float* Wt = (L == 0) ? tr1_W : trs_W + (size_t)(L - 1) * 256 * 256;
    const float* bt = (L == 0) ? tr1_b : trs_b + (size_t)(L - 1) * 256;
    float* slot = bnsums + (size_t)L * 512;

    gather_kernel<<<(N + 3) / 4, b256, 0, stream>>>(mF, off, csr, dis, bc, hA, N);
    bn_partial_kernel<<<1024, b256, 0, stream>>>(hA, slot, N);
    bn_finalize_kernel<<<1, b256, 0, stream>>>(slot, gg, gb, scalev, shiftv, 1.0f / (float)N);
    wsplit_fold_kernel<<<256, b256, 0, stream>>>(Wt, scalev, shiftv, bt, trHi, trLo, trBias);
    if (L < NL) {
      // fused tr(L) + conv(L+1) -> m_{L+1} (fp16)
      fused_gemm_kernel<256, true><<<nblk, b256, 0, stream>>>(
          hA, trHi, trLo, trBias, cvHi + (size_t)(L + 1) * 65536, cvLo + (size_t)(L + 1) * 65536,
          mF, N);
    } else {
      // final tr -> h (bfx2)
      gemm_mfma_kernel<256, true><<<nblk, b256, 0, stream>>>(hA, trHi, trLo, trBias, hB, N);
    }
  }

  pool_kernel<<<G, b256, 0, stream>>>(hB, batch, pooled, N);
  dim3 m1grid(G, 2);
  mlp1_kernel<<<m1grid, b256, 0, stream>>>(pooled, l1_W, l1_b, z1);
  mlp2_kernel<<<G, b256, 0, stream>>>(z1, l2_W, l2_b, z2);
  mlp3_kernel<<<G, 64, 0, stream>>>(z2, l3_W, l3_b, (float*)d_out);
}